// Round 9
// baseline (209.052 us; speedup 1.0000x reference)
//
#include <hip/hip_runtime.h>
#include <math.h>

#define FD 128
#define GATES 4
#define NB  128            // edge chunks (per-chunk private histograms)
#define NRH 2              // node ranges for hist
#define RSH_MAX 10048      // max nodes per hist range  (80.4 KB LDS)
#define RSF_MAX 20032      // fill: whole node range    (80.1 KB LDS)

typedef __attribute__((ext_vector_type(8))) short bf16x8;
typedef __attribute__((ext_vector_type(4))) float f32x4;

__device__ __forceinline__ float sigmoidf_(float v) {
    return 1.0f / (1.0f + expf(-v));
}

__device__ __forceinline__ unsigned short f2bf(float f) {
    unsigned int u = __builtin_bit_cast(unsigned int, f);
    u += 0x7fffu + ((u >> 16) & 1u);           // RNE (finite values)
    return (unsigned short)(u >> 16);
}
__device__ __forceinline__ float bflo(unsigned int u) {
    return __builtin_bit_cast(float, u << 16);
}
__device__ __forceinline__ float bfhi(unsigned int u) {
    return __builtin_bit_cast(float, u & 0xffff0000u);
}
__device__ __forceinline__ unsigned int pack2bf(float lo, float hi) {
    return (unsigned int)f2bf(lo) | ((unsigned int)f2bf(hi) << 16);
}

// ---- Kernel 1: fused cvt (x,h -> rows + A-frags kb 0-3/8-11 + flag) | pack_w
__global__ __launch_bounds__(256) void k_cvt_packw(
    const float* __restrict__ x, const float* __restrict__ h,
    const float* __restrict__ Wx, const float* __restrict__ Wh,
    unsigned int* __restrict__ xw, unsigned int* __restrict__ hw,
    unsigned short* __restrict__ Abf, unsigned short* __restrict__ Wbf,
    int* __restrict__ flagpart, int n16, int nfp) {

    if ((int)blockIdx.x >= nfp) {
        // ---- pack Wcat (512x512) into B-fragment order ----
        int frag = (blockIdx.x - nfp) * 4 + (threadIdx.x >> 6);   // 0..511
        int lane = threadIdx.x & 63;
        int cb = frag >> 4, kb = frag & 15;
        int col = cb * 16 + (lane & 15);
        int k0  = kb * 32 + (lane >> 4) * 8;

        int sel  = k0 >> 7;                // 0..3 : Wx0, Wx1, Wh0, Wh1
        int g    = col >> 7;
        int j    = col & (FD - 1);
        const float* Wb = (sel < 2) ? Wx : Wh;
        const float* p = Wb + (((size_t)g * 2 + (sel & 1)) * FD + (k0 & (FD - 1))) * FD + j;

        unsigned short outv[8];
        #pragma unroll
        for (int i = 0; i < 8; ++i) outv[i] = f2bf(p[(size_t)i * FD]);
        *reinterpret_cast<uint4*>(Wbf + (size_t)frag * 512 + lane * 8) =
            *reinterpret_cast<uint4*>(outv);
        return;
    }

    int t = blockIdx.x * 256 + threadIdx.x;
    bool nz = false;
    if (t < n16) {
        int r = t >> 4, o = t & 15;
        int slot = ((r & 15) + 16 * (o & 3)) * 8;
        size_t fb = ((size_t)(r >> 4) * 16) * 512;

        const float4* xp = reinterpret_cast<const float4*>(x) + (size_t)t * 2;
        float4 a = xp[0], bq = xp[1];
        uint4 ox;
        ox.x = pack2bf(a.x, a.y);   ox.y = pack2bf(a.z, a.w);
        ox.z = pack2bf(bq.x, bq.y); ox.w = pack2bf(bq.z, bq.w);
        reinterpret_cast<uint4*>(xw)[t] = ox;
        *reinterpret_cast<uint4*>(Abf + fb + (size_t)(o >> 2) * 512 + slot) = ox;

        const float4* hp = reinterpret_cast<const float4*>(h) + (size_t)t * 2;
        float4 hc = hp[0], hd = hp[1];
        nz = (hc.x != 0.f) | (hc.y != 0.f) | (hc.z != 0.f) | (hc.w != 0.f) |
             (hd.x != 0.f) | (hd.y != 0.f) | (hd.z != 0.f) | (hd.w != 0.f);
        uint4 oh;
        oh.x = pack2bf(hc.x, hc.y); oh.y = pack2bf(hc.z, hc.w);
        oh.z = pack2bf(hd.x, hd.y); oh.w = pack2bf(hd.z, hd.w);
        reinterpret_cast<uint4*>(hw)[t] = oh;
        *reinterpret_cast<uint4*>(Abf + fb + (size_t)(8 + (o >> 2)) * 512 + slot) = oh;
    }
    __shared__ int fsh;
    if (threadIdx.x == 0) fsh = 0;
    __syncthreads();
    unsigned long long m = __ballot(nz);
    if ((threadIdx.x & 63) == 0 && m) atomicOr(&fsh, 1);
    __syncthreads();
    if (threadIdx.x == 0) flagpart[blockIdx.x] = fsh;
}

// ---- Kernel 2: LDS-private histogram over (chunk b, node-range r) ----
__global__ __launch_bounds__(512) void k_hist_lds(
    const float* __restrict__ ew, const int* __restrict__ src,
    const int* __restrict__ dst,
    float* __restrict__ deg_priv, unsigned short* __restrict__ cnt_priv,
    int E, int n, int ech, int rs) {

    __shared__ float        degL[RSH_MAX];
    __shared__ unsigned int cntL[RSH_MAX];

    const int b = blockIdx.x & (NB - 1);
    const int r = blockIdx.x >> 7;            // NB==128
    const int base = r * rs;
    const int rse  = min(rs, n - base);

    for (int i = threadIdx.x; i < rse; i += 512) { degL[i] = 0.f; cntL[i] = 0u; }
    __syncthreads();

    const int e0 = b * ech, e1 = min(e0 + ech, E);
    for (int e = e0 + (int)threadIdx.x; e < e1; e += 512) {
        int s = src[e], d = dst[e];
        unsigned int rs_ = (unsigned int)(s - base);
        unsigned int rd_ = (unsigned int)(d - base);
        if (rs_ < (unsigned int)rse) atomicAdd(&degL[rs_], ew[e]);
        if (rd_ < (unsigned int)rse) atomicAdd(&cntL[rd_], 1u);
    }
    __syncthreads();

    float*          dp = deg_priv + (size_t)b * n + base;
    unsigned short* cp = cnt_priv + (size_t)b * n + base;
    for (int i = threadIdx.x; i < rse; i += 512) {
        dp[i] = degL[i];
        cp[i] = (unsigned short)cntL[i];
    }
}

// ---- Kernel 3: fold copies: dis = rsqrt(sum deg), cnt = sum cnt ----
__global__ void k_prep(const float* __restrict__ deg_priv,
                       const unsigned short* __restrict__ cnt_priv,
                       float* __restrict__ dis, int* __restrict__ cnt, int n) {
    int d = blockIdx.x * blockDim.x + threadIdx.x;
    if (d >= n) return;
    float s = 0.f; int ct = 0;
    #pragma unroll 4
    for (int b = 0; b < NB; ++b) {
        s  += deg_priv[(size_t)b * n + d];
        ct += (int)cnt_priv[(size_t)b * n + d];
    }
    dis[d] = (s > 0.0f) ? rsqrtf(fmaxf(s, 1e-12f)) : 0.0f;
    cnt[d] = ct;
}

// ---- Kernel 4: flag-OR + exclusive scan of cnt -> off (single block) ----
__global__ __launch_bounds__(1024) void k_scan(const int* __restrict__ cnt,
                                               int* __restrict__ off,
                                               const int* __restrict__ flagpart,
                                               int* __restrict__ hflag,
                                               int n, int nfp) {
    __shared__ int warp_sums[16];
    __shared__ int base_sh;
    __shared__ int fsh;
    if (threadIdx.x == 0) { base_sh = 0; fsh = 0; }
    __syncthreads();

    int fl = 0;
    for (int i = threadIdx.x; i < nfp; i += 1024) fl |= flagpart[i];
    if (fl) atomicOr(&fsh, 1);
    __syncthreads();
    if (threadIdx.x == 0) hflag[0] = fsh;

    const int lane = threadIdx.x & 63;
    const int wid  = threadIdx.x >> 6;

    for (int start = 0; start < n; start += 1024) {
        int i = start + (int)threadIdx.x;
        int v = (i < n) ? cnt[i] : 0;
        int s = v;
        #pragma unroll
        for (int d = 1; d < 64; d <<= 1) {
            int t = __shfl_up(s, d);
            if (lane >= d) s += t;
        }
        if (lane == 63) warp_sums[wid] = s;
        __syncthreads();
        if (wid == 0 && lane < 16) {
            int ws = warp_sums[lane];
            #pragma unroll
            for (int d = 1; d < 16; d <<= 1) {
                int t = __shfl_up(ws, d);
                if (lane >= d) ws += t;
            }
            warp_sums[lane] = ws;
        }
        __syncthreads();
        int wbase = (wid > 0) ? warp_sums[wid - 1] : 0;
        int excl  = base_sh + wbase + (s - v);
        if (i < n) off[i] = excl;
        int chunk_total = warp_sums[15];
        __syncthreads();
        if (threadIdx.x == 0) base_sh += chunk_total;
        __syncthreads();
    }
    if (threadIdx.x == 0) off[n] = base_sh;
}

// ---- Kernel 5: column scan: curb[b][d] = off[d] + prefix_b(cnt_priv) ----
__global__ void k_colscan(const unsigned short* __restrict__ cnt_priv,
                          const int* __restrict__ off,
                          int* __restrict__ curb, int n) {
    int d = blockIdx.x * blockDim.x + threadIdx.x;
    if (d >= n) return;
    int run = off[d];
    #pragma unroll 4
    for (int b = 0; b < NB; ++b) {
        curb[(size_t)b * n + d] = run;
        run += (int)cnt_priv[(size_t)b * n + d];
    }
}

// ---- Kernel 6: bucket fill, zero device atomics, packed (src,w) ----
__global__ __launch_bounds__(512) void k_fill_lds(
    const float* __restrict__ ew, const int* __restrict__ src,
    const int* __restrict__ dst, const float* __restrict__ dis,
    const int* __restrict__ curb, int2* __restrict__ epk,
    int E, int n, int ech) {

    __shared__ unsigned int curL[RSF_MAX];

    const int b = blockIdx.x;      // single node range covers all n
    for (int i = threadIdx.x; i < n; i += 512) curL[i] = 0u;
    __syncthreads();

    const int e0 = b * ech, e1 = min(e0 + ech, E);
    for (int e = e0 + (int)threadIdx.x; e < e1; e += 512) {
        int d = dst[e];
        int s = src[e];
        float w = -dis[s] * ew[e] * dis[d];
        int local = (int)atomicAdd(&curL[d], 1u);
        int p = curb[(size_t)b * n + d] + local;
        epk[p] = make_int2(s, __builtin_bit_cast(int, w));
    }
}

// ---- Kernel 7: gather -> writes tx/th A-fragments (kb 4-7, 12-15) directly
__global__ __launch_bounds__(256) void k_gather_bf(
    const unsigned int* __restrict__ xw, const unsigned int* __restrict__ hw,
    const int* __restrict__ off, const int2* __restrict__ epk,
    const int* __restrict__ hflag,
    unsigned short* __restrict__ Abf, int n) {

    int d    = blockIdx.x * 4 + (threadIdx.x >> 6);
    int lane = threadIdx.x & 63;
    if (d >= n) return;
    const bool hasH = (*hflag) != 0;

    int p0 = off[d], p1 = off[d + 1];
    float ax0 = 0.f, ax1 = 0.f, ah0 = 0.f, ah1 = 0.f;

    if (!hasH) {
        for (int base = p0; base < p1; base += 64) {
            int cnt = min(64, p1 - base);
            int2 my = make_int2(0, 0);
            if (lane < cnt) my = epk[base + lane];
            int   sm = my.x;
            float wm = __builtin_bit_cast(float, my.y);
            int k = 0;
            for (; k + 4 <= cnt; k += 4) {
                int   s0 = __shfl(sm, k),     s1 = __shfl(sm, k + 1);
                int   s2 = __shfl(sm, k + 2), s3 = __shfl(sm, k + 3);
                float w0 = __shfl(wm, k),     w1 = __shfl(wm, k + 1);
                float w2 = __shfl(wm, k + 2), w3 = __shfl(wm, k + 3);
                unsigned int u0 = xw[s0 * 64 + lane];
                unsigned int u1 = xw[s1 * 64 + lane];
                unsigned int u2 = xw[s2 * 64 + lane];
                unsigned int u3 = xw[s3 * 64 + lane];
                ax0 = fmaf(w0, bflo(u0), ax0); ax1 = fmaf(w0, bfhi(u0), ax1);
                ax0 = fmaf(w1, bflo(u1), ax0); ax1 = fmaf(w1, bfhi(u1), ax1);
                ax0 = fmaf(w2, bflo(u2), ax0); ax1 = fmaf(w2, bfhi(u2), ax1);
                ax0 = fmaf(w3, bflo(u3), ax0); ax1 = fmaf(w3, bfhi(u3), ax1);
            }
            for (; k < cnt; ++k) {
                int s = __shfl(sm, k);
                float w = __shfl(wm, k);
                unsigned int u = xw[s * 64 + lane];
                ax0 = fmaf(w, bflo(u), ax0); ax1 = fmaf(w, bfhi(u), ax1);
            }
        }
    } else {
        for (int base = p0; base < p1; base += 64) {
            int cnt = min(64, p1 - base);
            int2 my = make_int2(0, 0);
            if (lane < cnt) my = epk[base + lane];
            int   sm = my.x;
            float wm = __builtin_bit_cast(float, my.y);
            int k = 0;
            for (; k + 2 <= cnt; k += 2) {
                int   s0 = __shfl(sm, k), s1 = __shfl(sm, k + 1);
                float w0 = __shfl(wm, k), w1 = __shfl(wm, k + 1);
                unsigned int u0 = xw[s0 * 64 + lane];
                unsigned int v0 = hw[s0 * 64 + lane];
                unsigned int u1 = xw[s1 * 64 + lane];
                unsigned int v1 = hw[s1 * 64 + lane];
                ax0 = fmaf(w0, bflo(u0), ax0); ax1 = fmaf(w0, bfhi(u0), ax1);
                ah0 = fmaf(w0, bflo(v0), ah0); ah1 = fmaf(w0, bfhi(v0), ah1);
                ax0 = fmaf(w1, bflo(u1), ax0); ax1 = fmaf(w1, bfhi(u1), ax1);
                ah0 = fmaf(w1, bflo(v1), ah0); ah1 = fmaf(w1, bfhi(v1), ah1);
            }
            for (; k < cnt; ++k) {
                int s = __shfl(sm, k);
                float w = __shfl(wm, k);
                unsigned int u = xw[s * 64 + lane];
                unsigned int v = hw[s * 64 + lane];
                ax0 = fmaf(w, bflo(u), ax0); ax1 = fmaf(w, bfhi(u), ax1);
                ah0 = fmaf(w, bflo(v), ah0); ah1 = fmaf(w, bfhi(v), ah1);
            }
        }
    }

    unsigned int* Au = (unsigned int*)Abf;
    size_t fragT = (size_t)(d >> 4) * 16 + 4 + (lane >> 4);
    int slotu = ((d & 15) + 16 * ((lane >> 2) & 3)) * 4 + (lane & 3);
    Au[fragT * 256 + slotu] = pack2bf(ax0, ax1);
    if (hasH) Au[(fragT + 8) * 256 + slotu] = pack2bf(ah0, ah1);
}

// ---- Kernel 8: fused MFMA GEMM + LSTM epilogue ----
// Wave: 16 rows x 512 cols. acc[cf], cf = g*8 + jj. A-frags loaded once,
// B streamed from L2-resident Wbf. Lane holds all 4 gates for its
// 4 rows x 8 cols -> LSTM math in-register, direct output stores.
template<int KBMAX>
__device__ __forceinline__ void gemm_lstm_body(
    const unsigned short* __restrict__ Abf, const unsigned short* __restrict__ Wbf,
    const float* __restrict__ c, const float* __restrict__ bias,
    const float* __restrict__ wc, float* __restrict__ out,
    int n, int rt, int lane) {

    bf16x8 a[KBMAX];
    const unsigned short* ab = Abf + (size_t)rt * 16 * 512 + lane * 8;
    #pragma unroll
    for (int kb = 0; kb < KBMAX; ++kb)
        a[kb] = *reinterpret_cast<const bf16x8*>(ab + (size_t)kb * 512);

    f32x4 acc[32];
    #pragma unroll
    for (int cf = 0; cf < 32; ++cf) acc[cf] = (f32x4)0.0f;

    #pragma unroll
    for (int cf = 0; cf < 32; ++cf) {
        const unsigned short* bb = Wbf + (size_t)cf * 16 * 512 + lane * 8;
        #pragma unroll
        for (int kb = 0; kb < KBMAX; ++kb) {
            bf16x8 bv = *reinterpret_cast<const bf16x8*>(bb + (size_t)kb * 512);
            acc[cf] = __builtin_amdgcn_mfma_f32_16x16x32_bf16(a[kb], bv, acc[cf], 0, 0, 0);
        }
    }

    const int rbase = rt * 16 + (lane >> 4) * 4;
    const int colj  = lane & 15;
    const size_t NH = (size_t)n * FD;

    #pragma unroll
    for (int q = 0; q < 4; ++q) {
        int r = rbase + q;
        if (r >= n) continue;
        #pragma unroll
        for (int jj = 0; jj < 8; ++jj) {
            int col = jj * 16 + colj;
            float cv = c[(size_t)r * FD + col];
            float gi = acc[0 * 8 + jj][q] + wc[0 * FD + col] * cv + bias[0 * FD + col];
            float gf = acc[1 * 8 + jj][q] + wc[1 * FD + col] * cv + bias[1 * FD + col];
            float gg = acc[2 * 8 + jj][q] + bias[2 * FD + col];
            float iv = sigmoidf_(gi);
            float fv = sigmoidf_(gf);
            float cn = fv * cv + iv * tanhf(gg);
            float go = acc[3 * 8 + jj][q] + wc[2 * FD + col] * cn + bias[3 * FD + col];
            float hn = sigmoidf_(go) * tanhf(cn);
            size_t o = (size_t)r * FD + col;
            out[o]          = hn;
            out[NH + o]     = hn;
            out[2 * NH + o] = cn;
        }
    }
}

__global__ __launch_bounds__(256) void k_gemm_lstm(
    const unsigned short* __restrict__ Abf, const unsigned short* __restrict__ Wbf,
    const int* __restrict__ hflag,
    const float* __restrict__ c, const float* __restrict__ bias,
    const float* __restrict__ wc, float* __restrict__ out, int n) {

    int rt   = blockIdx.x * 4 + (threadIdx.x >> 6);
    int lane = threadIdx.x & 63;
    if (*hflag)
        gemm_lstm_body<16>(Abf, Wbf, c, bias, wc, out, n, rt, lane);
    else
        gemm_lstm_body<8>(Abf, Wbf, c, bias, wc, out, n, rt, lane);
}

extern "C" void kernel_launch(void* const* d_in, const int* in_sizes, int n_in,
                              void* d_out, int out_size, void* d_ws, size_t ws_size,
                              hipStream_t stream) {
    const float* x   = (const float*)d_in[0];
    const float* ew  = (const float*)d_in[1];
    const float* h   = (const float*)d_in[2];
    const float* c   = (const float*)d_in[3];
    const float* Wx  = (const float*)d_in[4];
    const float* Wh  = (const float*)d_in[5];
    const float* b   = (const float*)d_in[6];
    const float* wc  = (const float*)d_in[7];
    const int*   src = (const int*)d_in[8];
    const int*   dst = (const int*)d_in[9];

    const int n = in_sizes[0] / FD;   // 20000
    const int E = in_sizes[1];        // 640000

    const int Mpad = (n + 63) & ~63;              // 20032
    const int ech  = (E + NB - 1) / NB;           // 5000
    const int rsh  = (n + NRH - 1) / NRH;         // 10000 (<= RSH_MAX)
    const int n16  = n * 16;
    const int nfp  = (n16 + 255) / 256;           // cvt block count

    // ---- workspace layout (all regions disjoint; ws is 256MB) ----
    float* dis      = (float*)d_ws;                        // n
    int*   cnt      = (int*)(dis + n);                     // n
    int*   off      = cnt + n;                             // n+4
    int*   hflag    = off + n + 4;                         // 4
    int*   flagpart = hflag + 4;                           // 1280 (pad)
    int2*  epk      = (int2*)(flagpart + 1280);            // E
    unsigned int* xw = (unsigned int*)(epk + E);           // n*64
    unsigned int* hw = xw + (size_t)n * 64;                // n*64
    unsigned short* Abf = (unsigned short*)(hw + (size_t)n * 64);  // Mpad*512
    unsigned short* Wbf = Abf + (size_t)Mpad * 512;        // 512*512
    int*   curb     = (int*)(Wbf + 512 * 512);             // NB*n
    float* deg_priv = (float*)(curb + (size_t)NB * n);     // NB*n
    unsigned short* cnt_priv = (unsigned short*)(deg_priv + (size_t)NB * n); // NB*n

    k_cvt_packw<<<nfp + 128, 256, 0, stream>>>(x, h, Wx, Wh, xw, hw, Abf, Wbf,
                                               flagpart, n16, nfp);
    k_hist_lds<<<NRH * NB, 512, 0, stream>>>(ew, src, dst, deg_priv, cnt_priv, E, n, ech, rsh);
    k_prep<<<(n + 255) / 256, 256, 0, stream>>>(deg_priv, cnt_priv, dis, cnt, n);
    k_scan<<<1, 1024, 0, stream>>>(cnt, off, flagpart, hflag, n, nfp);
    k_colscan<<<(n + 255) / 256, 256, 0, stream>>>(cnt_priv, off, curb, n);
    k_fill_lds<<<NB, 512, 0, stream>>>(ew, src, dst, dis, curb, epk, E, n, ech);
    k_gather_bf<<<(n + 3) / 4, 256, 0, stream>>>(xw, hw, off, epk, hflag, Abf, n);

    k_gemm_lstm<<<Mpad / 64, 256, 0, stream>>>(Abf, Wbf, hflag, c, b, wc, (float*)d_out, n);
}

// Round 10
// 138.308 us; speedup vs baseline: 1.5115x; 1.5115x over previous
//
#include <hip/hip_runtime.h>
#include <math.h>

#define FD 128
#define GATES 4
#define NB  128            // edge chunks (per-chunk private histograms)
#define NRH 2              // node ranges for hist
#define RSH_MAX 10048      // max nodes per hist range  (80.4 KB LDS)
#define RSF_MAX 20032      // fill: whole node range    (80.1 KB LDS)

typedef __attribute__((ext_vector_type(8))) short bf16x8;
typedef __attribute__((ext_vector_type(4))) float f32x4;

__device__ __forceinline__ float sigmoidf_(float v) {
    return 1.0f / (1.0f + expf(-v));
}

__device__ __forceinline__ unsigned short f2bf(float f) {
    unsigned int u = __builtin_bit_cast(unsigned int, f);
    u += 0x7fffu + ((u >> 16) & 1u);           // RNE (finite values)
    return (unsigned short)(u >> 16);
}
__device__ __forceinline__ float bflo(unsigned int u) {
    return __builtin_bit_cast(float, u << 16);
}
__device__ __forceinline__ float bfhi(unsigned int u) {
    return __builtin_bit_cast(float, u & 0xffff0000u);
}
__device__ __forceinline__ unsigned int pack2bf(float lo, float hi) {
    return (unsigned int)f2bf(lo) | ((unsigned int)f2bf(hi) << 16);
}

// ---- Kernel 1: fused cvt (x,h -> rows + A-frags kb 0-3/8-11 + flag) | pack_w
__global__ __launch_bounds__(256) void k_cvt_packw(
    const float* __restrict__ x, const float* __restrict__ h,
    const float* __restrict__ Wx, const float* __restrict__ Wh,
    unsigned int* __restrict__ xw, unsigned int* __restrict__ hw,
    unsigned short* __restrict__ Abf, unsigned short* __restrict__ Wbf,
    int* __restrict__ flagpart, int n16, int nfp) {

    if ((int)blockIdx.x >= nfp) {
        int frag = (blockIdx.x - nfp) * 4 + (threadIdx.x >> 6);   // 0..511
        int lane = threadIdx.x & 63;
        int cb = frag >> 4, kb = frag & 15;
        int col = cb * 16 + (lane & 15);
        int k0  = kb * 32 + (lane >> 4) * 8;

        int sel  = k0 >> 7;                // 0..3 : Wx0, Wx1, Wh0, Wh1
        int g    = col >> 7;
        int j    = col & (FD - 1);
        const float* Wb = (sel < 2) ? Wx : Wh;
        const float* p = Wb + (((size_t)g * 2 + (sel & 1)) * FD + (k0 & (FD - 1))) * FD + j;

        unsigned short outv[8];
        #pragma unroll
        for (int i = 0; i < 8; ++i) outv[i] = f2bf(p[(size_t)i * FD]);
        *reinterpret_cast<uint4*>(Wbf + (size_t)frag * 512 + lane * 8) =
            *reinterpret_cast<uint4*>(outv);
        return;
    }

    int t = blockIdx.x * 256 + threadIdx.x;
    bool nz = false;
    if (t < n16) {
        int r = t >> 4, o = t & 15;
        int slot = ((r & 15) + 16 * (o & 3)) * 8;
        size_t fb = ((size_t)(r >> 4) * 16) * 512;

        const float4* xp = reinterpret_cast<const float4*>(x) + (size_t)t * 2;
        float4 a = xp[0], bq = xp[1];
        uint4 ox;
        ox.x = pack2bf(a.x, a.y);   ox.y = pack2bf(a.z, a.w);
        ox.z = pack2bf(bq.x, bq.y); ox.w = pack2bf(bq.z, bq.w);
        reinterpret_cast<uint4*>(xw)[t] = ox;
        *reinterpret_cast<uint4*>(Abf + fb + (size_t)(o >> 2) * 512 + slot) = ox;

        const float4* hp = reinterpret_cast<const float4*>(h) + (size_t)t * 2;
        float4 hc = hp[0], hd = hp[1];
        nz = (hc.x != 0.f) | (hc.y != 0.f) | (hc.z != 0.f) | (hc.w != 0.f) |
             (hd.x != 0.f) | (hd.y != 0.f) | (hd.z != 0.f) | (hd.w != 0.f);
        uint4 oh;
        oh.x = pack2bf(hc.x, hc.y); oh.y = pack2bf(hc.z, hc.w);
        oh.z = pack2bf(hd.x, hd.y); oh.w = pack2bf(hd.z, hd.w);
        reinterpret_cast<uint4*>(hw)[t] = oh;
        *reinterpret_cast<uint4*>(Abf + fb + (size_t)(8 + (o >> 2)) * 512 + slot) = oh;
    }
    __shared__ int fsh;
    if (threadIdx.x == 0) fsh = 0;
    __syncthreads();
    unsigned long long m = __ballot(nz);
    if ((threadIdx.x & 63) == 0 && m) atomicOr(&fsh, 1);
    __syncthreads();
    if (threadIdx.x == 0) flagpart[blockIdx.x] = fsh;
}

// ---- Kernel 2: LDS-private histogram over (chunk b, node-range r) ----
__global__ __launch_bounds__(512) void k_hist_lds(
    const float* __restrict__ ew, const int* __restrict__ src,
    const int* __restrict__ dst,
    float* __restrict__ deg_priv, unsigned short* __restrict__ cnt_priv,
    int E, int n, int ech, int rs) {

    __shared__ float        degL[RSH_MAX];
    __shared__ unsigned int cntL[RSH_MAX];

    const int b = blockIdx.x & (NB - 1);
    const int r = blockIdx.x >> 7;            // NB==128
    const int base = r * rs;
    const int rse  = min(rs, n - base);

    for (int i = threadIdx.x; i < rse; i += 512) { degL[i] = 0.f; cntL[i] = 0u; }
    __syncthreads();

    const int e0 = b * ech, e1 = min(e0 + ech, E);
    for (int e = e0 + (int)threadIdx.x; e < e1; e += 512) {
        int s = src[e], d = dst[e];
        unsigned int rs_ = (unsigned int)(s - base);
        unsigned int rd_ = (unsigned int)(d - base);
        if (rs_ < (unsigned int)rse) atomicAdd(&degL[rs_], ew[e]);
        if (rd_ < (unsigned int)rse) atomicAdd(&cntL[rd_], 1u);
    }
    __syncthreads();

    float*          dp = deg_priv + (size_t)b * n + base;
    unsigned short* cp = cnt_priv + (size_t)b * n + base;
    for (int i = threadIdx.x; i < rse; i += 512) {
        dp[i] = degL[i];
        cp[i] = (unsigned short)cntL[i];
    }
}

// ---- Kernel 3: fold copies: dis = rsqrt(sum deg), cnt = sum cnt ----
__global__ void k_prep(const float* __restrict__ deg_priv,
                       const unsigned short* __restrict__ cnt_priv,
                       float* __restrict__ dis, int* __restrict__ cnt, int n) {
    int d = blockIdx.x * blockDim.x + threadIdx.x;
    if (d >= n) return;
    float s = 0.f; int ct = 0;
    #pragma unroll 4
    for (int b = 0; b < NB; ++b) {
        s  += deg_priv[(size_t)b * n + d];
        ct += (int)cnt_priv[(size_t)b * n + d];
    }
    dis[d] = (s > 0.0f) ? rsqrtf(fmaxf(s, 1e-12f)) : 0.0f;
    cnt[d] = ct;
}

// ---- Kernel 4: flag-OR + exclusive scan of cnt -> off (single block) ----
__global__ __launch_bounds__(1024) void k_scan(const int* __restrict__ cnt,
                                               int* __restrict__ off,
                                               const int* __restrict__ flagpart,
                                               int* __restrict__ hflag,
                                               int n, int nfp) {
    __shared__ int warp_sums[16];
    __shared__ int base_sh;
    __shared__ int fsh;
    if (threadIdx.x == 0) { base_sh = 0; fsh = 0; }
    __syncthreads();

    int fl = 0;
    for (int i = threadIdx.x; i < nfp; i += 1024) fl |= flagpart[i];
    if (fl) atomicOr(&fsh, 1);
    __syncthreads();
    if (threadIdx.x == 0) hflag[0] = fsh;

    const int lane = threadIdx.x & 63;
    const int wid  = threadIdx.x >> 6;

    for (int start = 0; start < n; start += 1024) {
        int i = start + (int)threadIdx.x;
        int v = (i < n) ? cnt[i] : 0;
        int s = v;
        #pragma unroll
        for (int d = 1; d < 64; d <<= 1) {
            int t = __shfl_up(s, d);
            if (lane >= d) s += t;
        }
        if (lane == 63) warp_sums[wid] = s;
        __syncthreads();
        if (wid == 0 && lane < 16) {
            int ws = warp_sums[lane];
            #pragma unroll
            for (int d = 1; d < 16; d <<= 1) {
                int t = __shfl_up(ws, d);
                if (lane >= d) ws += t;
            }
            warp_sums[lane] = ws;
        }
        __syncthreads();
        int wbase = (wid > 0) ? warp_sums[wid - 1] : 0;
        int excl  = base_sh + wbase + (s - v);
        if (i < n) off[i] = excl;
        int chunk_total = warp_sums[15];
        __syncthreads();
        if (threadIdx.x == 0) base_sh += chunk_total;
        __syncthreads();
    }
    if (threadIdx.x == 0) off[n] = base_sh;
}

// ---- Kernel 5: column scan: curb[b][d] = off[d] + prefix_b(cnt_priv) ----
__global__ void k_colscan(const unsigned short* __restrict__ cnt_priv,
                          const int* __restrict__ off,
                          int* __restrict__ curb, int n) {
    int d = blockIdx.x * blockDim.x + threadIdx.x;
    if (d >= n) return;
    int run = off[d];
    #pragma unroll 4
    for (int b = 0; b < NB; ++b) {
        curb[(size_t)b * n + d] = run;
        run += (int)cnt_priv[(size_t)b * n + d];
    }
}

// ---- Kernel 6: bucket fill, zero device atomics, packed (src,w) ----
__global__ __launch_bounds__(512) void k_fill_lds(
    const float* __restrict__ ew, const int* __restrict__ src,
    const int* __restrict__ dst, const float* __restrict__ dis,
    const int* __restrict__ curb, int2* __restrict__ epk,
    int E, int n, int ech) {

    __shared__ unsigned int curL[RSF_MAX];

    const int b = blockIdx.x;      // single node range covers all n
    for (int i = threadIdx.x; i < n; i += 512) curL[i] = 0u;
    __syncthreads();

    const int e0 = b * ech, e1 = min(e0 + ech, E);
    for (int e = e0 + (int)threadIdx.x; e < e1; e += 512) {
        int d = dst[e];
        int s = src[e];
        float w = -dis[s] * ew[e] * dis[d];
        int local = (int)atomicAdd(&curL[d], 1u);
        int p = curb[(size_t)b * n + d] + local;
        epk[p] = make_int2(s, __builtin_bit_cast(int, w));
    }
}

// ---- Kernel 7: gather -> writes tx/th A-fragments (kb 4-7, 12-15) directly
__global__ __launch_bounds__(256) void k_gather_bf(
    const unsigned int* __restrict__ xw, const unsigned int* __restrict__ hw,
    const int* __restrict__ off, const int2* __restrict__ epk,
    const int* __restrict__ hflag,
    unsigned short* __restrict__ Abf, int n) {

    int d    = blockIdx.x * 4 + (threadIdx.x >> 6);
    int lane = threadIdx.x & 63;
    if (d >= n) return;
    const bool hasH = (*hflag) != 0;

    int p0 = off[d], p1 = off[d + 1];
    float ax0 = 0.f, ax1 = 0.f, ah0 = 0.f, ah1 = 0.f;

    if (!hasH) {
        for (int base = p0; base < p1; base += 64) {
            int cnt = min(64, p1 - base);
            int2 my = make_int2(0, 0);
            if (lane < cnt) my = epk[base + lane];
            int   sm = my.x;
            float wm = __builtin_bit_cast(float, my.y);
            int k = 0;
            for (; k + 4 <= cnt; k += 4) {
                int   s0 = __shfl(sm, k),     s1 = __shfl(sm, k + 1);
                int   s2 = __shfl(sm, k + 2), s3 = __shfl(sm, k + 3);
                float w0 = __shfl(wm, k),     w1 = __shfl(wm, k + 1);
                float w2 = __shfl(wm, k + 2), w3 = __shfl(wm, k + 3);
                unsigned int u0 = xw[s0 * 64 + lane];
                unsigned int u1 = xw[s1 * 64 + lane];
                unsigned int u2 = xw[s2 * 64 + lane];
                unsigned int u3 = xw[s3 * 64 + lane];
                ax0 = fmaf(w0, bflo(u0), ax0); ax1 = fmaf(w0, bfhi(u0), ax1);
                ax0 = fmaf(w1, bflo(u1), ax0); ax1 = fmaf(w1, bfhi(u1), ax1);
                ax0 = fmaf(w2, bflo(u2), ax0); ax1 = fmaf(w2, bfhi(u2), ax1);
                ax0 = fmaf(w3, bflo(u3), ax0); ax1 = fmaf(w3, bfhi(u3), ax1);
            }
            for (; k < cnt; ++k) {
                int s = __shfl(sm, k);
                float w = __shfl(wm, k);
                unsigned int u = xw[s * 64 + lane];
                ax0 = fmaf(w, bflo(u), ax0); ax1 = fmaf(w, bfhi(u), ax1);
            }
        }
    } else {
        for (int base = p0; base < p1; base += 64) {
            int cnt = min(64, p1 - base);
            int2 my = make_int2(0, 0);
            if (lane < cnt) my = epk[base + lane];
            int   sm = my.x;
            float wm = __builtin_bit_cast(float, my.y);
            int k = 0;
            for (; k + 2 <= cnt; k += 2) {
                int   s0 = __shfl(sm, k), s1 = __shfl(sm, k + 1);
                float w0 = __shfl(wm, k), w1 = __shfl(wm, k + 1);
                unsigned int u0 = xw[s0 * 64 + lane];
                unsigned int v0 = hw[s0 * 64 + lane];
                unsigned int u1 = xw[s1 * 64 + lane];
                unsigned int v1 = hw[s1 * 64 + lane];
                ax0 = fmaf(w0, bflo(u0), ax0); ax1 = fmaf(w0, bfhi(u0), ax1);
                ah0 = fmaf(w0, bflo(v0), ah0); ah1 = fmaf(w0, bfhi(v0), ah1);
                ax0 = fmaf(w1, bflo(u1), ax0); ax1 = fmaf(w1, bfhi(u1), ax1);
                ah0 = fmaf(w1, bflo(v1), ah0); ah1 = fmaf(w1, bfhi(v1), ah1);
            }
            for (; k < cnt; ++k) {
                int s = __shfl(sm, k);
                float w = __shfl(wm, k);
                unsigned int u = xw[s * 64 + lane];
                unsigned int v = hw[s * 64 + lane];
                ax0 = fmaf(w, bflo(u), ax0); ax1 = fmaf(w, bfhi(u), ax1);
                ah0 = fmaf(w, bflo(v), ah0); ah1 = fmaf(w, bfhi(v), ah1);
            }
        }
    }

    unsigned int* Au = (unsigned int*)Abf;
    size_t fragT = (size_t)(d >> 4) * 16 + 4 + (lane >> 4);
    int slotu = ((d & 15) + 16 * ((lane >> 2) & 3)) * 4 + (lane & 3);
    Au[fragT * 256 + slotu] = pack2bf(ax0, ax1);
    if (hasH) Au[(fragT + 8) * 256 + slotu] = pack2bf(ah0, ah1);
}

// ---- Kernel 8: fused MFMA GEMM + LSTM epilogue (round-8 geometry) ----
// Wave: 64 rows x {16 cols of each of the 4 gates}: col-frags cf = g*8 + jj.
// acc[mi][g] (16 f32x4, same budget as proven 64x64 GEMM); 16 independent
// MFMAs per kb. Lane ends with all 4 gate pre-activations for its
// (row, col) pairs -> in-register LSTM, direct output stores.
__global__ __launch_bounds__(256) void k_gemm_lstm(
    const unsigned short* __restrict__ Abf, const unsigned short* __restrict__ Wbf,
    const int* __restrict__ hflag,
    const float* __restrict__ c, const float* __restrict__ bias,
    const float* __restrict__ wc, float* __restrict__ out, int n) {

    int wg   = blockIdx.x * 4 + (threadIdx.x >> 6);
    int lane = threadIdx.x & 63;
    int rt = wg >> 3;          // row tile (64 rows)
    int jj = wg & 7;           // 16-col slice within each gate
    const int kbmax = (*hflag) ? 16 : 8;

    f32x4 acc[4][4];
    #pragma unroll
    for (int mi = 0; mi < 4; ++mi)
        #pragma unroll
        for (int g = 0; g < 4; ++g)
            acc[mi][g] = (f32x4)0.0f;

    const size_t aoff = ((size_t)(rt * 4) * 16) * 512 + lane * 8;

    for (int kb = 0; kb < kbmax; ++kb) {
        bf16x8 a[4], b[4];
        #pragma unroll
        for (int mi = 0; mi < 4; ++mi)
            a[mi] = *reinterpret_cast<const bf16x8*>(Abf + aoff + (size_t)(mi * 16 + kb) * 512);
        #pragma unroll
        for (int g = 0; g < 4; ++g)
            b[g] = *reinterpret_cast<const bf16x8*>(
                Wbf + ((size_t)(g * 8 + jj) * 16 + kb) * 512 + lane * 8);
        #pragma unroll
        for (int mi = 0; mi < 4; ++mi)
            #pragma unroll
            for (int g = 0; g < 4; ++g)
                acc[mi][g] = __builtin_amdgcn_mfma_f32_16x16x32_bf16(
                                 a[mi], b[g], acc[mi][g], 0, 0, 0);
    }

    const int r0   = rt * 64;
    const int col  = jj * 16 + (lane & 15);
    const size_t NH = (size_t)n * FD;
    const float wc0 = wc[0 * FD + col], wc1 = wc[1 * FD + col], wc2 = wc[2 * FD + col];
    const float b0  = bias[0 * FD + col], b1 = bias[1 * FD + col];
    const float b2  = bias[2 * FD + col], b3 = bias[3 * FD + col];

    #pragma unroll
    for (int mi = 0; mi < 4; ++mi) {
        #pragma unroll
        for (int q = 0; q < 4; ++q) {
            int r = r0 + mi * 16 + (lane >> 4) * 4 + q;
            if (r >= n) continue;
            float cv = c[(size_t)r * FD + col];
            float gi = acc[mi][0][q] + wc0 * cv + b0;
            float gf = acc[mi][1][q] + wc1 * cv + b1;
            float gg = acc[mi][2][q] + b2;
            float iv = sigmoidf_(gi);
            float fv = sigmoidf_(gf);
            float cn = fv * cv + iv * tanhf(gg);
            float go = acc[mi][3][q] + wc2 * cn + b3;
            float hn = sigmoidf_(go) * tanhf(cn);
            size_t o = (size_t)r * FD + col;
            out[o]          = hn;
            out[NH + o]     = hn;
            out[2 * NH + o] = cn;
        }
    }
}

extern "C" void kernel_launch(void* const* d_in, const int* in_sizes, int n_in,
                              void* d_out, int out_size, void* d_ws, size_t ws_size,
                              hipStream_t stream) {
    const float* x   = (const float*)d_in[0];
    const float* ew  = (const float*)d_in[1];
    const float* h   = (const float*)d_in[2];
    const float* c   = (const float*)d_in[3];
    const float* Wx  = (const float*)d_in[4];
    const float* Wh  = (const float*)d_in[5];
    const float* b   = (const float*)d_in[6];
    const float* wc  = (const float*)d_in[7];
    const int*   src = (const int*)d_in[8];
    const int*   dst = (const int*)d_in[9];

    const int n = in_sizes[0] / FD;   // 20000
    const int E = in_sizes[1];        // 640000

    const int Mpad = (n + 63) & ~63;              // 20032
    const int ech  = (E + NB - 1) / NB;           // 5000
    const int rsh  = (n + NRH - 1) / NRH;         // 10000 (<= RSH_MAX)
    const int n16  = n * 16;
    const int nfp  = (n16 + 255) / 256;           // cvt block count

    // ---- workspace layout (all regions disjoint; ws is 256MB) ----
    float* dis      = (float*)d_ws;                        // n
    int*   cnt      = (int*)(dis + n);                     // n
    int*   off      = cnt + n;                             // n+4
    int*   hflag    = off + n + 4;                         // 4
    int*   flagpart = hflag + 4;                           // 1280 (pad)
    int2*  epk      = (int2*)(flagpart + 1280);            // E
    unsigned int* xw = (unsigned int*)(epk + E);           // n*64
    unsigned int* hw = xw + (size_t)n * 64;                // n*64
    unsigned short* Abf = (unsigned short*)(hw + (size_t)n * 64);  // Mpad*512
    unsigned short* Wbf = Abf + (size_t)Mpad * 512;        // 512*512
    int*   curb     = (int*)(Wbf + 512 * 512);             // NB*n
    float* deg_priv = (float*)(curb + (size_t)NB * n);     // NB*n
    unsigned short* cnt_priv = (unsigned short*)(deg_priv + (size_t)NB * n); // NB*n

    k_cvt_packw<<<nfp + 128, 256, 0, stream>>>(x, h, Wx, Wh, xw, hw, Abf, Wbf,
                                               flagpart, n16, nfp);
    k_hist_lds<<<NRH * NB, 512, 0, stream>>>(ew, src, dst, deg_priv, cnt_priv, E, n, ech, rsh);
    k_prep<<<(n + 255) / 256, 256, 0, stream>>>(deg_priv, cnt_priv, dis, cnt, n);
    k_scan<<<1, 1024, 0, stream>>>(cnt, off, flagpart, hflag, n, nfp);
    k_colscan<<<(n + 255) / 256, 256, 0, stream>>>(cnt_priv, off, curb, n);
    k_fill_lds<<<NB, 512, 0, stream>>>(ew, src, dst, dis, curb, epk, E, n, ech);
    k_gather_bf<<<(n + 3) / 4, 256, 0, stream>>>(xw, hw, off, epk, hflag, Abf, n);

    k_gemm_lstm<<<(Mpad / 64) * 2, 256, 0, stream>>>(Abf, Wbf, hflag, c, b, wc,
                                                     (float*)d_out, n);
}

// Round 11
// 121.624 us; speedup vs baseline: 1.7188x; 1.1372x over previous
//
#include <hip/hip_runtime.h>
#include <math.h>

#define FD 128
#define GATES 4
#define NB   128           // edge chunks (per-chunk private histograms)
#define NMAX 20032         // max node count supported by LDS-resident hist/fill

typedef __attribute__((ext_vector_type(8))) short bf16x8;
typedef __attribute__((ext_vector_type(4))) float f32x4;

__device__ __forceinline__ float sigmoidf_(float v) {
    return 1.0f / (1.0f + expf(-v));
}

__device__ __forceinline__ unsigned short f2bf(float f) {
    unsigned int u = __builtin_bit_cast(unsigned int, f);
    u += 0x7fffu + ((u >> 16) & 1u);           // RNE (finite values)
    return (unsigned short)(u >> 16);
}
__device__ __forceinline__ float bflo(unsigned int u) {
    return __builtin_bit_cast(float, u << 16);
}
__device__ __forceinline__ float bfhi(unsigned int u) {
    return __builtin_bit_cast(float, u & 0xffff0000u);
}
__device__ __forceinline__ unsigned int pack2bf(float lo, float hi) {
    return (unsigned int)f2bf(lo) | ((unsigned int)f2bf(hi) << 16);
}

// ---- Kernel 1: fused cvt (x,h -> rows + A-frags kb 0-3/8-11 + flag) | pack_w
__global__ __launch_bounds__(256) void k_cvt_packw(
    const float* __restrict__ x, const float* __restrict__ h,
    const float* __restrict__ Wx, const float* __restrict__ Wh,
    unsigned int* __restrict__ xw, unsigned int* __restrict__ hw,
    unsigned short* __restrict__ Abf, unsigned short* __restrict__ Wbf,
    int* __restrict__ flagpart, int n16, int nfp) {

    if ((int)blockIdx.x >= nfp) {
        int frag = (blockIdx.x - nfp) * 4 + (threadIdx.x >> 6);   // 0..511
        int lane = threadIdx.x & 63;
        int cb = frag >> 4, kb = frag & 15;
        int col = cb * 16 + (lane & 15);
        int k0  = kb * 32 + (lane >> 4) * 8;

        int sel  = k0 >> 7;                // 0..3 : Wx0, Wx1, Wh0, Wh1
        int g    = col >> 7;
        int j    = col & (FD - 1);
        const float* Wb = (sel < 2) ? Wx : Wh;
        const float* p = Wb + (((size_t)g * 2 + (sel & 1)) * FD + (k0 & (FD - 1))) * FD + j;

        unsigned short outv[8];
        #pragma unroll
        for (int i = 0; i < 8; ++i) outv[i] = f2bf(p[(size_t)i * FD]);
        *reinterpret_cast<uint4*>(Wbf + (size_t)frag * 512 + lane * 8) =
            *reinterpret_cast<uint4*>(outv);
        return;
    }

    int t = blockIdx.x * 256 + threadIdx.x;
    bool nz = false;
    if (t < n16) {
        int r = t >> 4, o = t & 15;
        int slot = ((r & 15) + 16 * (o & 3)) * 8;
        size_t fb = ((size_t)(r >> 4) * 16) * 512;

        const float4* xp = reinterpret_cast<const float4*>(x) + (size_t)t * 2;
        float4 a = xp[0], bq = xp[1];
        uint4 ox;
        ox.x = pack2bf(a.x, a.y);   ox.y = pack2bf(a.z, a.w);
        ox.z = pack2bf(bq.x, bq.y); ox.w = pack2bf(bq.z, bq.w);
        reinterpret_cast<uint4*>(xw)[t] = ox;
        *reinterpret_cast<uint4*>(Abf + fb + (size_t)(o >> 2) * 512 + slot) = ox;

        const float4* hp = reinterpret_cast<const float4*>(h) + (size_t)t * 2;
        float4 hc = hp[0], hd = hp[1];
        nz = (hc.x != 0.f) | (hc.y != 0.f) | (hc.z != 0.f) | (hc.w != 0.f) |
             (hd.x != 0.f) | (hd.y != 0.f) | (hd.z != 0.f) | (hd.w != 0.f);
        uint4 oh;
        oh.x = pack2bf(hc.x, hc.y); oh.y = pack2bf(hc.z, hc.w);
        oh.z = pack2bf(hd.x, hd.y); oh.w = pack2bf(hd.z, hd.w);
        reinterpret_cast<uint4*>(hw)[t] = oh;
        *reinterpret_cast<uint4*>(Abf + fb + (size_t)(8 + (o >> 2)) * 512 + slot) = oh;
    }
    __shared__ int fsh;
    if (threadIdx.x == 0) fsh = 0;
    __syncthreads();
    unsigned long long m = __ballot(nz);
    if ((threadIdx.x & 63) == 0 && m) atomicOr(&fsh, 1);
    __syncthreads();
    if (threadIdx.x == 0) flagpart[blockIdx.x] = fsh;
}

// ---- Kernel 2: single-pass LDS-private histogram per edge chunk b ----
// degL f32 per node; dst counts packed 2 x u16 per u32 (count <= ech < 65536).
__global__ __launch_bounds__(512) void k_hist_lds(
    const float* __restrict__ ew, const int* __restrict__ src,
    const int* __restrict__ dst,
    float* __restrict__ deg_priv, unsigned short* __restrict__ cnt_priv,
    int E, int n, int ech) {

    __shared__ float        degL[NMAX];
    __shared__ unsigned int cntP[NMAX / 2];

    const int b  = blockIdx.x;
    const int nh = (n + 1) >> 1;
    for (int i = threadIdx.x; i < n;  i += 512) degL[i] = 0.f;
    for (int i = threadIdx.x; i < nh; i += 512) cntP[i] = 0u;
    __syncthreads();

    const int e0 = b * ech, e1 = min(e0 + ech, E);
    for (int e = e0 + (int)threadIdx.x; e < e1; e += 512) {
        int s = src[e], d = dst[e];
        atomicAdd(&degL[s], ew[e]);
        atomicAdd(&cntP[d >> 1], (d & 1) ? 0x10000u : 1u);
    }
    __syncthreads();

    float*          dp = deg_priv + (size_t)b * n;
    unsigned short* cp = cnt_priv + (size_t)b * n;
    for (int i = threadIdx.x; i < n; i += 512) dp[i] = degL[i];
    for (int i = threadIdx.x; i < n; i += 512) {
        unsigned int v = cntP[i >> 1];
        cp[i] = (unsigned short)((i & 1) ? (v >> 16) : (v & 0xffffu));
    }
}

// ---- Kernel 3: fold copies -> dis, cnt; per-block partial sums; hflag OR ----
__global__ __launch_bounds__(256) void k_prep(
    const float* __restrict__ deg_priv, const unsigned short* __restrict__ cnt_priv,
    float* __restrict__ dis, int* __restrict__ cnt, int* __restrict__ partial,
    const int* __restrict__ flagpart, int* __restrict__ hflag, int n, int nfp) {

    int d = blockIdx.x * 256 + threadIdx.x;
    int ct = 0;
    if (d < n) {
        float s = 0.f;
        #pragma unroll 4
        for (int b = 0; b < NB; ++b) {
            s  += deg_priv[(size_t)b * n + d];
            ct += (int)cnt_priv[(size_t)b * n + d];
        }
        dis[d] = (s > 0.0f) ? rsqrtf(fmaxf(s, 1e-12f)) : 0.0f;
        cnt[d] = ct;
    }

    __shared__ int red[4];
    int lane = threadIdx.x & 63, wid = threadIdx.x >> 6;
    int v = ct;
    #pragma unroll
    for (int o = 32; o > 0; o >>= 1) v += __shfl_down(v, o);
    if (lane == 0) red[wid] = v;
    __syncthreads();
    if (threadIdx.x == 0)
        partial[blockIdx.x] = red[0] + red[1] + red[2] + red[3];

    if (blockIdx.x == 0) {
        __shared__ int fsh;
        if (threadIdx.x == 0) fsh = 0;
        __syncthreads();
        int fl = 0;
        for (int i = threadIdx.x; i < nfp; i += 256) fl |= flagpart[i];
        if (fl) atomicOr(&fsh, 1);
        __syncthreads();
        if (threadIdx.x == 0) hflag[0] = fsh;
    }
}

// ---- Kernel 4: merged scan+colscan: off[d] and curb[b][d], fully parallel ----
__global__ __launch_bounds__(256) void k_colscan2(
    const unsigned short* __restrict__ cnt_priv, const int* __restrict__ cnt,
    const int* __restrict__ partial,
    int* __restrict__ off, int* __restrict__ curb, int n, int E) {

    const int j = blockIdx.x;
    const int d = j * 256 + (int)threadIdx.x;
    const int lane = threadIdx.x & 63, wid = threadIdx.x >> 6;

    // global base = sum of partial[0..j)
    __shared__ int redw[4];
    int pv = 0;
    for (int p = threadIdx.x; p < j; p += 256) pv += partial[p];
    int v = pv;
    #pragma unroll
    for (int o = 32; o > 0; o >>= 1) v += __shfl_down(v, o);
    if (lane == 0) redw[wid] = v;
    __syncthreads();
    const int base = redw[0] + redw[1] + redw[2] + redw[3];

    // block-local exclusive scan of cnt
    int myc = (d < n) ? cnt[d] : 0;
    int s = myc;
    #pragma unroll
    for (int o = 1; o < 64; o <<= 1) {
        int t = __shfl_up(s, o);
        if (lane >= o) s += t;
    }
    __shared__ int wsum[4];
    if (lane == 63) wsum[wid] = s;
    __syncthreads();
    int wbase = 0;
    for (int wi = 0; wi < wid; ++wi) wbase += wsum[wi];
    int excl = base + wbase + (s - myc);

    if (d < n) {
        off[d] = excl;
        int run = excl;
        #pragma unroll 4
        for (int b = 0; b < NB; ++b) {
            curb[(size_t)b * n + d] = run;
            run += (int)cnt_priv[(size_t)b * n + d];
        }
    }
    if (j == 0 && threadIdx.x == 0) off[n] = E;
}

// ---- Kernel 5: bucket fill, zero device atomics, packed (src,w) ----
__global__ __launch_bounds__(512) void k_fill_lds(
    const float* __restrict__ ew, const int* __restrict__ src,
    const int* __restrict__ dst, const float* __restrict__ dis,
    const int* __restrict__ curb, int2* __restrict__ epk,
    int E, int n, int ech) {

    __shared__ unsigned int curL[NMAX];

    const int b = blockIdx.x;
    for (int i = threadIdx.x; i < n; i += 512) curL[i] = 0u;
    __syncthreads();

    const int e0 = b * ech, e1 = min(e0 + ech, E);
    for (int e = e0 + (int)threadIdx.x; e < e1; e += 512) {
        int d = dst[e];
        int s = src[e];
        float w = -dis[s] * ew[e] * dis[d];
        int local = (int)atomicAdd(&curL[d], 1u);
        int p = curb[(size_t)b * n + d] + local;
        epk[p] = make_int2(s, __builtin_bit_cast(int, w));
    }
}

// ---- Kernel 6: gather -> writes tx/th A-fragments (kb 4-7, 12-15) directly
__global__ __launch_bounds__(256) void k_gather_bf(
    const unsigned int* __restrict__ xw, const unsigned int* __restrict__ hw,
    const int* __restrict__ off, const int2* __restrict__ epk,
    const int* __restrict__ hflag,
    unsigned short* __restrict__ Abf, int n) {

    int d    = blockIdx.x * 4 + (threadIdx.x >> 6);
    int lane = threadIdx.x & 63;
    if (d >= n) return;
    const bool hasH = (*hflag) != 0;

    int p0 = off[d], p1 = off[d + 1];
    float ax0 = 0.f, ax1 = 0.f, ah0 = 0.f, ah1 = 0.f;

    if (!hasH) {
        for (int base = p0; base < p1; base += 64) {
            int cnt = min(64, p1 - base);
            int2 my = make_int2(0, 0);
            if (lane < cnt) my = epk[base + lane];
            int   sm = my.x;
            float wm = __builtin_bit_cast(float, my.y);
            int k = 0;
            for (; k + 4 <= cnt; k += 4) {
                int   s0 = __shfl(sm, k),     s1 = __shfl(sm, k + 1);
                int   s2 = __shfl(sm, k + 2), s3 = __shfl(sm, k + 3);
                float w0 = __shfl(wm, k),     w1 = __shfl(wm, k + 1);
                float w2 = __shfl(wm, k + 2), w3 = __shfl(wm, k + 3);
                unsigned int u0 = xw[s0 * 64 + lane];
                unsigned int u1 = xw[s1 * 64 + lane];
                unsigned int u2 = xw[s2 * 64 + lane];
                unsigned int u3 = xw[s3 * 64 + lane];
                ax0 = fmaf(w0, bflo(u0), ax0); ax1 = fmaf(w0, bfhi(u0), ax1);
                ax0 = fmaf(w1, bflo(u1), ax0); ax1 = fmaf(w1, bfhi(u1), ax1);
                ax0 = fmaf(w2, bflo(u2), ax0); ax1 = fmaf(w2, bfhi(u2), ax1);
                ax0 = fmaf(w3, bflo(u3), ax0); ax1 = fmaf(w3, bfhi(u3), ax1);
            }
            for (; k < cnt; ++k) {
                int s = __shfl(sm, k);
                float w = __shfl(wm, k);
                unsigned int u = xw[s * 64 + lane];
                ax0 = fmaf(w, bflo(u), ax0); ax1 = fmaf(w, bfhi(u), ax1);
            }
        }
    } else {
        for (int base = p0; base < p1; base += 64) {
            int cnt = min(64, p1 - base);
            int2 my = make_int2(0, 0);
            if (lane < cnt) my = epk[base + lane];
            int   sm = my.x;
            float wm = __builtin_bit_cast(float, my.y);
            int k = 0;
            for (; k + 2 <= cnt; k += 2) {
                int   s0 = __shfl(sm, k), s1 = __shfl(sm, k + 1);
                float w0 = __shfl(wm, k), w1 = __shfl(wm, k + 1);
                unsigned int u0 = xw[s0 * 64 + lane];
                unsigned int v0 = hw[s0 * 64 + lane];
                unsigned int u1 = xw[s1 * 64 + lane];
                unsigned int v1 = hw[s1 * 64 + lane];
                ax0 = fmaf(w0, bflo(u0), ax0); ax1 = fmaf(w0, bfhi(u0), ax1);
                ah0 = fmaf(w0, bflo(v0), ah0); ah1 = fmaf(w0, bfhi(v0), ah1);
                ax0 = fmaf(w1, bflo(u1), ax0); ax1 = fmaf(w1, bfhi(u1), ax1);
                ah0 = fmaf(w1, bflo(v1), ah0); ah1 = fmaf(w1, bfhi(v1), ah1);
            }
            for (; k < cnt; ++k) {
                int s = __shfl(sm, k);
                float w = __shfl(wm, k);
                unsigned int u = xw[s * 64 + lane];
                unsigned int v = hw[s * 64 + lane];
                ax0 = fmaf(w, bflo(u), ax0); ax1 = fmaf(w, bfhi(u), ax1);
                ah0 = fmaf(w, bflo(v), ah0); ah1 = fmaf(w, bfhi(v), ah1);
            }
        }
    }

    unsigned int* Au = (unsigned int*)Abf;
    size_t fragT = (size_t)(d >> 4) * 16 + 4 + (lane >> 4);
    int slotu = ((d & 15) + 16 * ((lane >> 2) & 3)) * 4 + (lane & 3);
    Au[fragT * 256 + slotu] = pack2bf(ax0, ax1);
    if (hasH) Au[(fragT + 8) * 256 + slotu] = pack2bf(ah0, ah1);
}

// ---- Kernel 7: fused MFMA GEMM + LSTM epilogue ----
// Wave: 64 rows x {16 cols of each of the 4 gates}: col-frags cf = g*8 + jj.
__global__ __launch_bounds__(256) void k_gemm_lstm(
    const unsigned short* __restrict__ Abf, const unsigned short* __restrict__ Wbf,
    const int* __restrict__ hflag,
    const float* __restrict__ c, const float* __restrict__ bias,
    const float* __restrict__ wc, float* __restrict__ out, int n) {

    int wg   = blockIdx.x * 4 + (threadIdx.x >> 6);
    int lane = threadIdx.x & 63;
    int rt = wg >> 3;          // row tile (64 rows)
    int jj = wg & 7;           // 16-col slice within each gate
    const int kbmax = (*hflag) ? 16 : 8;

    f32x4 acc[4][4];
    #pragma unroll
    for (int mi = 0; mi < 4; ++mi)
        #pragma unroll
        for (int g = 0; g < 4; ++g)
            acc[mi][g] = (f32x4)0.0f;

    const size_t aoff = ((size_t)(rt * 4) * 16) * 512 + lane * 8;

    for (int kb = 0; kb < kbmax; ++kb) {
        bf16x8 a[4], b[4];
        #pragma unroll
        for (int mi = 0; mi < 4; ++mi)
            a[mi] = *reinterpret_cast<const bf16x8*>(Abf + aoff + (size_t)(mi * 16 + kb) * 512);
        #pragma unroll
        for (int g = 0; g < 4; ++g)
            b[g] = *reinterpret_cast<const bf16x8*>(
                Wbf + ((size_t)(g * 8 + jj) * 16 + kb) * 512 + lane * 8);
        #pragma unroll
        for (int mi = 0; mi < 4; ++mi)
            #pragma unroll
            for (int g = 0; g < 4; ++g)
                acc[mi][g] = __builtin_amdgcn_mfma_f32_16x16x32_bf16(
                                 a[mi], b[g], acc[mi][g], 0, 0, 0);
    }

    const int r0   = rt * 64;
    const int col  = jj * 16 + (lane & 15);
    const size_t NH = (size_t)n * FD;
    const float wc0 = wc[0 * FD + col], wc1 = wc[1 * FD + col], wc2 = wc[2 * FD + col];
    const float b0  = bias[0 * FD + col], b1 = bias[1 * FD + col];
    const float b2  = bias[2 * FD + col], b3 = bias[3 * FD + col];

    #pragma unroll
    for (int mi = 0; mi < 4; ++mi) {
        #pragma unroll
        for (int q = 0; q < 4; ++q) {
            int r = r0 + mi * 16 + (lane >> 4) * 4 + q;
            if (r >= n) continue;
            float cv = c[(size_t)r * FD + col];
            float gi = acc[mi][0][q] + wc0 * cv + b0;
            float gf = acc[mi][1][q] + wc1 * cv + b1;
            float gg = acc[mi][2][q] + b2;
            float iv = sigmoidf_(gi);
            float fv = sigmoidf_(gf);
            float cn = fv * cv + iv * tanhf(gg);
            float go = acc[mi][3][q] + wc2 * cn + b3;
            float hn = sigmoidf_(go) * tanhf(cn);
            size_t o = (size_t)r * FD + col;
            out[o]          = hn;
            out[NH + o]     = hn;
            out[2 * NH + o] = cn;
        }
    }
}

extern "C" void kernel_launch(void* const* d_in, const int* in_sizes, int n_in,
                              void* d_out, int out_size, void* d_ws, size_t ws_size,
                              hipStream_t stream) {
    const float* x   = (const float*)d_in[0];
    const float* ew  = (const float*)d_in[1];
    const float* h   = (const float*)d_in[2];
    const float* c   = (const float*)d_in[3];
    const float* Wx  = (const float*)d_in[4];
    const float* Wh  = (const float*)d_in[5];
    const float* b   = (const float*)d_in[6];
    const float* wc  = (const float*)d_in[7];
    const int*   src = (const int*)d_in[8];
    const int*   dst = (const int*)d_in[9];

    const int n = in_sizes[0] / FD;   // 20000  (<= NMAX)
    const int E = in_sizes[1];        // 640000

    const int Mpad = (n + 63) & ~63;              // 20032
    const int ech  = (E + NB - 1) / NB;           // 5000
    const int n16  = n * 16;
    const int nfp  = (n16 + 255) / 256;           // cvt block count
    const int NP   = (n + 255) / 256;             // prep/colscan2 block count

    // ---- workspace layout (all regions disjoint; ws is 256MB) ----
    float* dis      = (float*)d_ws;                        // n
    int*   cnt      = (int*)(dis + n);                     // n
    int*   off      = cnt + n;                             // n+4
    int*   hflag    = off + n + 4;                         // 4
    int*   flagpart = hflag + 4;                           // 1280 (pad)
    int*   partial  = flagpart + 1280;                     // 128 (pad)
    int2*  epk      = (int2*)(partial + 128);              // E
    unsigned int* xw = (unsigned int*)(epk + E);           // n*64
    unsigned int* hw = xw + (size_t)n * 64;                // n*64
    unsigned short* Abf = (unsigned short*)(hw + (size_t)n * 64);  // Mpad*512
    unsigned short* Wbf = Abf + (size_t)Mpad * 512;        // 512*512
    int*   curb     = (int*)(Wbf + 512 * 512);             // NB*n
    float* deg_priv = (float*)(curb + (size_t)NB * n);     // NB*n
    unsigned short* cnt_priv = (unsigned short*)(deg_priv + (size_t)NB * n); // NB*n

    k_cvt_packw<<<nfp + 128, 256, 0, stream>>>(x, h, Wx, Wh, xw, hw, Abf, Wbf,
                                               flagpart, n16, nfp);
    k_hist_lds<<<NB, 512, 0, stream>>>(ew, src, dst, deg_priv, cnt_priv, E, n, ech);
    k_prep<<<NP, 256, 0, stream>>>(deg_priv, cnt_priv, dis, cnt, partial,
                                   flagpart, hflag, n, nfp);
    k_colscan2<<<NP, 256, 0, stream>>>(cnt_priv, cnt, partial, off, curb, n, E);
    k_fill_lds<<<NB, 512, 0, stream>>>(ew, src, dst, dis, curb, epk, E, n, ech);
    k_gather_bf<<<(n + 3) / 4, 256, 0, stream>>>(xw, hw, off, epk, hflag, Abf, n);

    k_gemm_lstm<<<(Mpad / 64) * 2, 256, 0, stream>>>(Abf, Wbf, hflag, c, b, wc,
                                                     (float*)d_out, n);
}

// Round 12
// 115.029 us; speedup vs baseline: 1.8174x; 1.0573x over previous
//
#include <hip/hip_runtime.h>
#include <math.h>

#define FD 128
#define GATES 4
#define NB   128           // edge chunks (per-chunk private histograms)
#define NMAX 20032         // max node count supported by LDS-resident hist/fill

typedef __attribute__((ext_vector_type(8))) short bf16x8;
typedef __attribute__((ext_vector_type(4))) float f32x4;

__device__ __forceinline__ float sigmoidf_(float v) {
    return 1.0f / (1.0f + expf(-v));
}

__device__ __forceinline__ unsigned short f2bf(float f) {
    unsigned int u = __builtin_bit_cast(unsigned int, f);
    u += 0x7fffu + ((u >> 16) & 1u);           // RNE (finite values)
    return (unsigned short)(u >> 16);
}
__device__ __forceinline__ float bflo(unsigned int u) {
    return __builtin_bit_cast(float, u << 16);
}
__device__ __forceinline__ float bfhi(unsigned int u) {
    return __builtin_bit_cast(float, u & 0xffff0000u);
}
__device__ __forceinline__ unsigned int pack2bf(float lo, float hi) {
    return (unsigned int)f2bf(lo) | ((unsigned int)f2bf(hi) << 16);
}

// ---- Kernel 1: fused cvt (x,h -> rows + A-frags kb 0-3/8-11 + flag) | pack_w
__global__ __launch_bounds__(256) void k_cvt_packw(
    const float* __restrict__ x, const float* __restrict__ h,
    const float* __restrict__ Wx, const float* __restrict__ Wh,
    unsigned int* __restrict__ xw, unsigned int* __restrict__ hw,
    unsigned short* __restrict__ Abf, unsigned short* __restrict__ Wbf,
    int* __restrict__ flagpart, int n16, int nfp) {

    if ((int)blockIdx.x >= nfp) {
        int frag = (blockIdx.x - nfp) * 4 + (threadIdx.x >> 6);   // 0..511
        int lane = threadIdx.x & 63;
        int cb = frag >> 4, kb = frag & 15;
        int col = cb * 16 + (lane & 15);
        int k0  = kb * 32 + (lane >> 4) * 8;

        int sel  = k0 >> 7;                // 0..3 : Wx0, Wx1, Wh0, Wh1
        int g    = col >> 7;
        int j    = col & (FD - 1);
        const float* Wb = (sel < 2) ? Wx : Wh;
        const float* p = Wb + (((size_t)g * 2 + (sel & 1)) * FD + (k0 & (FD - 1))) * FD + j;

        unsigned short outv[8];
        #pragma unroll
        for (int i = 0; i < 8; ++i) outv[i] = f2bf(p[(size_t)i * FD]);
        *reinterpret_cast<uint4*>(Wbf + (size_t)frag * 512 + lane * 8) =
            *reinterpret_cast<uint4*>(outv);
        return;
    }

    int t = blockIdx.x * 256 + threadIdx.x;
    bool nz = false;
    if (t < n16) {
        int r = t >> 4, o = t & 15;
        int slot = ((r & 15) + 16 * (o & 3)) * 8;
        size_t fb = ((size_t)(r >> 4) * 16) * 512;

        const float4* xp = reinterpret_cast<const float4*>(x) + (size_t)t * 2;
        float4 a = xp[0], bq = xp[1];
        uint4 ox;
        ox.x = pack2bf(a.x, a.y);   ox.y = pack2bf(a.z, a.w);
        ox.z = pack2bf(bq.x, bq.y); ox.w = pack2bf(bq.z, bq.w);
        reinterpret_cast<uint4*>(xw)[t] = ox;
        *reinterpret_cast<uint4*>(Abf + fb + (size_t)(o >> 2) * 512 + slot) = ox;

        const float4* hp = reinterpret_cast<const float4*>(h) + (size_t)t * 2;
        float4 hc = hp[0], hd = hp[1];
        nz = (hc.x != 0.f) | (hc.y != 0.f) | (hc.z != 0.f) | (hc.w != 0.f) |
             (hd.x != 0.f) | (hd.y != 0.f) | (hd.z != 0.f) | (hd.w != 0.f);
        uint4 oh;
        oh.x = pack2bf(hc.x, hc.y); oh.y = pack2bf(hc.z, hc.w);
        oh.z = pack2bf(hd.x, hd.y); oh.w = pack2bf(hd.z, hd.w);
        reinterpret_cast<uint4*>(hw)[t] = oh;
        *reinterpret_cast<uint4*>(Abf + fb + (size_t)(8 + (o >> 2)) * 512 + slot) = oh;
    }
    __shared__ int fsh;
    if (threadIdx.x == 0) fsh = 0;
    __syncthreads();
    unsigned long long m = __ballot(nz);
    if ((threadIdx.x & 63) == 0 && m) atomicOr(&fsh, 1);
    __syncthreads();
    if (threadIdx.x == 0) flagpart[blockIdx.x] = fsh;
}

// ---- Kernel 2: single-pass LDS-private histogram per edge chunk b ----
// degL f32 per node; dst counts packed 2 x u16 per u32 (count <= ech < 65536).
// Block 0 also zeroes the global offset cursor (consumed later by k_fold).
__global__ __launch_bounds__(512) void k_hist_lds(
    const float* __restrict__ ew, const int* __restrict__ src,
    const int* __restrict__ dst,
    float* __restrict__ deg_priv, unsigned short* __restrict__ cnt_priv,
    int* __restrict__ cursor, int E, int n, int ech) {

    __shared__ float        degL[NMAX];
    __shared__ unsigned int cntP[NMAX / 2];

    if (blockIdx.x == 0 && threadIdx.x == 0) cursor[0] = 0;

    const int b  = blockIdx.x;
    const int nh = (n + 1) >> 1;
    for (int i = threadIdx.x; i < n;  i += 512) degL[i] = 0.f;
    for (int i = threadIdx.x; i < nh; i += 512) cntP[i] = 0u;
    __syncthreads();

    const int e0 = b * ech, e1 = min(e0 + ech, E);
    for (int e = e0 + (int)threadIdx.x; e < e1; e += 512) {
        int s = src[e], d = dst[e];
        atomicAdd(&degL[s], ew[e]);
        atomicAdd(&cntP[d >> 1], (d & 1) ? 0x10000u : 1u);
    }
    __syncthreads();

    float*          dp = deg_priv + (size_t)b * n;
    unsigned short* cp = cnt_priv + (size_t)b * n;
    for (int i = threadIdx.x; i < n; i += 512) dp[i] = degL[i];
    for (int i = threadIdx.x; i < n; i += 512) {
        unsigned int v = cntP[i >> 1];
        cp[i] = (unsigned short)((i & 1) ? (v >> 16) : (v & 0xffffu));
    }
}

// ---- Kernel 3: fold copies -> dis, cnt; allocate off via wave-agg atomic;
//      write per-chunk cursors curb; block 0 folds hflag OR. ----
__global__ __launch_bounds__(256) void k_fold(
    const float* __restrict__ deg_priv, const unsigned short* __restrict__ cnt_priv,
    float* __restrict__ dis, int* __restrict__ cnt, int* __restrict__ off,
    int* __restrict__ curb, int* __restrict__ cursor,
    const int* __restrict__ flagpart, int* __restrict__ hflag, int n, int nfp) {

    int d = blockIdx.x * 256 + threadIdx.x;
    int lane = threadIdx.x & 63;
    int ct = 0;
    if (d < n) {
        float s = 0.f;
        #pragma unroll 4
        for (int b = 0; b < NB; ++b) {
            s  += deg_priv[(size_t)b * n + d];
            ct += (int)cnt_priv[(size_t)b * n + d];
        }
        dis[d] = (s > 0.0f) ? rsqrtf(fmaxf(s, 1e-12f)) : 0.0f;
        cnt[d] = ct;
    }

    // wave-aggregated offset allocation (CSR regions need not be d-monotonic)
    int s_incl = ct;
    #pragma unroll
    for (int o = 1; o < 64; o <<= 1) {
        int t = __shfl_up(s_incl, o);
        if (lane >= o) s_incl += t;
    }
    int wtotal = __shfl(s_incl, 63);
    int base = 0;
    if (lane == 0) base = atomicAdd(cursor, wtotal);
    base = __shfl(base, 0);

    if (d < n) {
        int my0 = base + s_incl - ct;
        off[d] = my0;
        int run = my0;
        #pragma unroll 4
        for (int b = 0; b < NB; ++b) {
            curb[(size_t)b * n + d] = run;
            run += (int)cnt_priv[(size_t)b * n + d];   // L2-hot re-read
        }
    }

    if (blockIdx.x == 0) {
        __shared__ int fsh;
        if (threadIdx.x == 0) fsh = 0;
        __syncthreads();
        int fl = 0;
        for (int i = threadIdx.x; i < nfp; i += 256) fl |= flagpart[i];
        if (fl) atomicOr(&fsh, 1);
        __syncthreads();
        if (threadIdx.x == 0) hflag[0] = fsh;
    }
}

// ---- Kernel 4: bucket fill; cursor row staged in LDS (coalesced), then
//      LDS atomic allocation; zero device atomics. ----
__global__ __launch_bounds__(512) void k_fill_lds(
    const float* __restrict__ ew, const int* __restrict__ src,
    const int* __restrict__ dst, const float* __restrict__ dis,
    const int* __restrict__ curb, int2* __restrict__ epk,
    int E, int n, int ech) {

    __shared__ int curL[NMAX];

    const int b = blockIdx.x;
    const int* crow = curb + (size_t)b * n;
    for (int i = threadIdx.x; i < n; i += 512) curL[i] = crow[i];
    __syncthreads();

    const int e0 = b * ech, e1 = min(e0 + ech, E);
    for (int e = e0 + (int)threadIdx.x; e < e1; e += 512) {
        int d = dst[e];
        int s = src[e];
        float w = -dis[s] * ew[e] * dis[d];
        int p = atomicAdd(&curL[d], 1);
        epk[p] = make_int2(s, __builtin_bit_cast(int, w));
    }
}

// ---- Kernel 5: gather -> writes tx/th A-fragments (kb 4-7, 12-15) directly
__global__ __launch_bounds__(256) void k_gather_bf(
    const unsigned int* __restrict__ xw, const unsigned int* __restrict__ hw,
    const int* __restrict__ off, const int* __restrict__ cntv,
    const int2* __restrict__ epk, const int* __restrict__ hflag,
    unsigned short* __restrict__ Abf, int n) {

    int d    = blockIdx.x * 4 + (threadIdx.x >> 6);
    int lane = threadIdx.x & 63;
    if (d >= n) return;
    const bool hasH = (*hflag) != 0;

    int p0 = off[d], p1 = p0 + cntv[d];
    float ax0 = 0.f, ax1 = 0.f, ah0 = 0.f, ah1 = 0.f;

    if (!hasH) {
        for (int base = p0; base < p1; base += 64) {
            int cnt = min(64, p1 - base);
            int2 my = make_int2(0, 0);
            if (lane < cnt) my = epk[base + lane];
            int   sm = my.x;
            float wm = __builtin_bit_cast(float, my.y);
            int k = 0;
            for (; k + 4 <= cnt; k += 4) {
                int   s0 = __shfl(sm, k),     s1 = __shfl(sm, k + 1);
                int   s2 = __shfl(sm, k + 2), s3 = __shfl(sm, k + 3);
                float w0 = __shfl(wm, k),     w1 = __shfl(wm, k + 1);
                float w2 = __shfl(wm, k + 2), w3 = __shfl(wm, k + 3);
                unsigned int u0 = xw[s0 * 64 + lane];
                unsigned int u1 = xw[s1 * 64 + lane];
                unsigned int u2 = xw[s2 * 64 + lane];
                unsigned int u3 = xw[s3 * 64 + lane];
                ax0 = fmaf(w0, bflo(u0), ax0); ax1 = fmaf(w0, bfhi(u0), ax1);
                ax0 = fmaf(w1, bflo(u1), ax0); ax1 = fmaf(w1, bfhi(u1), ax1);
                ax0 = fmaf(w2, bflo(u2), ax0); ax1 = fmaf(w2, bfhi(u2), ax1);
                ax0 = fmaf(w3, bflo(u3), ax0); ax1 = fmaf(w3, bfhi(u3), ax1);
            }
            for (; k < cnt; ++k) {
                int s = __shfl(sm, k);
                float w = __shfl(wm, k);
                unsigned int u = xw[s * 64 + lane];
                ax0 = fmaf(w, bflo(u), ax0); ax1 = fmaf(w, bfhi(u), ax1);
            }
        }
    } else {
        for (int base = p0; base < p1; base += 64) {
            int cnt = min(64, p1 - base);
            int2 my = make_int2(0, 0);
            if (lane < cnt) my = epk[base + lane];
            int   sm = my.x;
            float wm = __builtin_bit_cast(float, my.y);
            int k = 0;
            for (; k + 2 <= cnt; k += 2) {
                int   s0 = __shfl(sm, k), s1 = __shfl(sm, k + 1);
                float w0 = __shfl(wm, k), w1 = __shfl(wm, k + 1);
                unsigned int u0 = xw[s0 * 64 + lane];
                unsigned int v0 = hw[s0 * 64 + lane];
                unsigned int u1 = xw[s1 * 64 + lane];
                unsigned int v1 = hw[s1 * 64 + lane];
                ax0 = fmaf(w0, bflo(u0), ax0); ax1 = fmaf(w0, bfhi(u0), ax1);
                ah0 = fmaf(w0, bflo(v0), ah0); ah1 = fmaf(w0, bfhi(v0), ah1);
                ax0 = fmaf(w1, bflo(u1), ax0); ax1 = fmaf(w1, bfhi(u1), ax1);
                ah0 = fmaf(w1, bflo(v1), ah0); ah1 = fmaf(w1, bfhi(v1), ah1);
            }
            for (; k < cnt; ++k) {
                int s = __shfl(sm, k);
                float w = __shfl(wm, k);
                unsigned int u = xw[s * 64 + lane];
                unsigned int v = hw[s * 64 + lane];
                ax0 = fmaf(w, bflo(u), ax0); ax1 = fmaf(w, bfhi(u), ax1);
                ah0 = fmaf(w, bflo(v), ah0); ah1 = fmaf(w, bfhi(v), ah1);
            }
        }
    }

    unsigned int* Au = (unsigned int*)Abf;
    size_t fragT = (size_t)(d >> 4) * 16 + 4 + (lane >> 4);
    int slotu = ((d & 15) + 16 * ((lane >> 2) & 3)) * 4 + (lane & 3);
    Au[fragT * 256 + slotu] = pack2bf(ax0, ax1);
    if (hasH) Au[(fragT + 8) * 256 + slotu] = pack2bf(ah0, ah1);
}

// ---- Kernel 6: fused MFMA GEMM + LSTM epilogue ----
// Wave: 64 rows x {16 cols of each of the 4 gates}: col-frags cf = g*8 + jj.
__global__ __launch_bounds__(256) void k_gemm_lstm(
    const unsigned short* __restrict__ Abf, const unsigned short* __restrict__ Wbf,
    const int* __restrict__ hflag,
    const float* __restrict__ c, const float* __restrict__ bias,
    const float* __restrict__ wc, float* __restrict__ out, int n) {

    int wg   = blockIdx.x * 4 + (threadIdx.x >> 6);
    int lane = threadIdx.x & 63;
    int rt = wg >> 3;          // row tile (64 rows)
    int jj = wg & 7;           // 16-col slice within each gate
    const int kbmax = (*hflag) ? 16 : 8;

    f32x4 acc[4][4];
    #pragma unroll
    for (int mi = 0; mi < 4; ++mi)
        #pragma unroll
        for (int g = 0; g < 4; ++g)
            acc[mi][g] = (f32x4)0.0f;

    const size_t aoff = ((size_t)(rt * 4) * 16) * 512 + lane * 8;

    for (int kb = 0; kb < kbmax; ++kb) {
        bf16x8 a[4], b[4];
        #pragma unroll
        for (int mi = 0; mi < 4; ++mi)
            a[mi] = *reinterpret_cast<const bf16x8*>(Abf + aoff + (size_t)(mi * 16 + kb) * 512);
        #pragma unroll
        for (int g = 0; g < 4; ++g)
            b[g] = *reinterpret_cast<const bf16x8*>(
                Wbf + ((size_t)(g * 8 + jj) * 16 + kb) * 512 + lane * 8);
        #pragma unroll
        for (int mi = 0; mi < 4; ++mi)
            #pragma unroll
            for (int g = 0; g < 4; ++g)
                acc[mi][g] = __builtin_amdgcn_mfma_f32_16x16x32_bf16(
                                 a[mi], b[g], acc[mi][g], 0, 0, 0);
    }

    const int r0   = rt * 64;
    const int col  = jj * 16 + (lane & 15);
    const size_t NH = (size_t)n * FD;
    const float wc0 = wc[0 * FD + col], wc1 = wc[1 * FD + col], wc2 = wc[2 * FD + col];
    const float b0  = bias[0 * FD + col], b1 = bias[1 * FD + col];
    const float b2  = bias[2 * FD + col], b3 = bias[3 * FD + col];

    #pragma unroll
    for (int mi = 0; mi < 4; ++mi) {
        #pragma unroll
        for (int q = 0; q < 4; ++q) {
            int r = r0 + mi * 16 + (lane >> 4) * 4 + q;
            if (r >= n) continue;
            float cv = c[(size_t)r * FD + col];
            float gi = acc[mi][0][q] + wc0 * cv + b0;
            float gf = acc[mi][1][q] + wc1 * cv + b1;
            float gg = acc[mi][2][q] + b2;
            float iv = sigmoidf_(gi);
            float fv = sigmoidf_(gf);
            float cn = fv * cv + iv * tanhf(gg);
            float go = acc[mi][3][q] + wc2 * cn + b3;
            float hn = sigmoidf_(go) * tanhf(cn);
            size_t o = (size_t)r * FD + col;
            out[o]          = hn;
            out[NH + o]     = hn;
            out[2 * NH + o] = cn;
        }
    }
}

extern "C" void kernel_launch(void* const* d_in, const int* in_sizes, int n_in,
                              void* d_out, int out_size, void* d_ws, size_t ws_size,
                              hipStream_t stream) {
    const float* x   = (const float*)d_in[0];
    const float* ew  = (const float*)d_in[1];
    const float* h   = (const float*)d_in[2];
    const float* c   = (const float*)d_in[3];
    const float* Wx  = (const float*)d_in[4];
    const float* Wh  = (const float*)d_in[5];
    const float* b   = (const float*)d_in[6];
    const float* wc  = (const float*)d_in[7];
    const int*   src = (const int*)d_in[8];
    const int*   dst = (const int*)d_in[9];

    const int n = in_sizes[0] / FD;   // 20000  (<= NMAX)
    const int E = in_sizes[1];        // 640000

    const int Mpad = (n + 63) & ~63;              // 20032
    const int ech  = (E + NB - 1) / NB;           // 5000
    const int n16  = n * 16;
    const int nfp  = (n16 + 255) / 256;           // cvt block count
    const int NP   = (n + 255) / 256;             // fold block count

    // ---- workspace layout (all regions disjoint; ws is 256MB) ----
    float* dis      = (float*)d_ws;                        // n
    int*   cnt      = (int*)(dis + n);                     // n
    int*   off      = cnt + n;                             // n+4
    int*   hflag    = off + n + 4;                         // 4
    int*   cursor   = hflag + 4;                           // 4
    int*   flagpart = cursor + 4;                          // 1280 (pad)
    int2*  epk      = (int2*)(flagpart + 1280);            // E
    unsigned int* xw = (unsigned int*)(epk + E);           // n*64
    unsigned int* hw = xw + (size_t)n * 64;                // n*64
    unsigned short* Abf = (unsigned short*)(hw + (size_t)n * 64);  // Mpad*512
    unsigned short* Wbf = Abf + (size_t)Mpad * 512;        // 512*512
    int*   curb     = (int*)(Wbf + 512 * 512);             // NB*n
    float* deg_priv = (float*)(curb + (size_t)NB * n);     // NB*n
    unsigned short* cnt_priv = (unsigned short*)(deg_priv + (size_t)NB * n); // NB*n

    k_cvt_packw<<<nfp + 128, 256, 0, stream>>>(x, h, Wx, Wh, xw, hw, Abf, Wbf,
                                               flagpart, n16, nfp);
    k_hist_lds<<<NB, 512, 0, stream>>>(ew, src, dst, deg_priv, cnt_priv, cursor, E, n, ech);
    k_fold<<<NP, 256, 0, stream>>>(deg_priv, cnt_priv, dis, cnt, off, curb, cursor,
                                   flagpart, hflag, n, nfp);
    k_fill_lds<<<NB, 512, 0, stream>>>(ew, src, dst, dis, curb, epk, E, n, ech);
    k_gather_bf<<<(n + 3) / 4, 256, 0, stream>>>(xw, hw, off, cnt, epk, hflag, Abf, n);

    k_gemm_lstm<<<(Mpad / 64) * 2, 256, 0, stream>>>(Abf, Wbf, hflag, c, b, wc,
                                                     (float*)d_out, n);
}

// Round 13
// 113.386 us; speedup vs baseline: 1.8437x; 1.0145x over previous
//
#include <hip/hip_runtime.h>
#include <math.h>

#define FD 128
#define GATES 4
#define NB   128           // edge chunks (per-chunk private histograms)
#define NMAX 20032         // max node count supported by LDS-resident hist/fill

typedef __attribute__((ext_vector_type(8))) short bf16x8;
typedef __attribute__((ext_vector_type(4))) float f32x4;

__device__ __forceinline__ float sigmoidf_(float v) {
    return 1.0f / (1.0f + expf(-v));
}

__device__ __forceinline__ unsigned short f2bf(float f) {
    unsigned int u = __builtin_bit_cast(unsigned int, f);
    u += 0x7fffu + ((u >> 16) & 1u);           // RNE (finite values)
    return (unsigned short)(u >> 16);
}
__device__ __forceinline__ float bflo(unsigned int u) {
    return __builtin_bit_cast(float, u << 16);
}
__device__ __forceinline__ float bfhi(unsigned int u) {
    return __builtin_bit_cast(float, u & 0xffff0000u);
}
__device__ __forceinline__ unsigned int pack2bf(float lo, float hi) {
    return (unsigned int)f2bf(lo) | ((unsigned int)f2bf(hi) << 16);
}

// ---- Kernel 1: single-pass LDS-private histogram per edge chunk b ----
// degL f32 per node; dst counts packed 2 x u16 per u32 (count <= ech < 65536).
// Block 0 zeroes the offset cursor and hflag (consumed by later dispatches).
__global__ __launch_bounds__(512) void k_hist_lds(
    const float* __restrict__ ew, const int* __restrict__ src,
    const int* __restrict__ dst,
    float* __restrict__ deg_priv, unsigned short* __restrict__ cnt_priv,
    int* __restrict__ cursor, int* __restrict__ hflag, int E, int n, int ech) {

    __shared__ float        degL[NMAX];
    __shared__ unsigned int cntP[NMAX / 2];

    if (blockIdx.x == 0 && threadIdx.x == 0) { cursor[0] = 0; hflag[0] = 0; }

    const int b  = blockIdx.x;
    const int nh = (n + 1) >> 1;
    for (int i = threadIdx.x; i < n;  i += 512) degL[i] = 0.f;
    for (int i = threadIdx.x; i < nh; i += 512) cntP[i] = 0u;
    __syncthreads();

    const int e0 = b * ech, e1 = min(e0 + ech, E);
    for (int e = e0 + (int)threadIdx.x; e < e1; e += 512) {
        int s = src[e], d = dst[e];
        atomicAdd(&degL[s], ew[e]);
        atomicAdd(&cntP[d >> 1], (d & 1) ? 0x10000u : 1u);
    }
    __syncthreads();

    float*          dp = deg_priv + (size_t)b * n;
    unsigned short* cp = cnt_priv + (size_t)b * n;
    for (int i = threadIdx.x; i < n; i += 512) dp[i] = degL[i];
    for (int i = threadIdx.x; i < n; i += 512) {
        unsigned int v = cntP[i >> 1];
        cp[i] = (unsigned short)((i & 1) ? (v >> 16) : (v & 0xffffu));
    }
}

// ---- Kernel 2: merged cvt | pack_w | fold (independent grid sections) ----
// cvt:  x,h -> bf16 rows + A-frags kb 0-3/8-11 + per-block h-flag parts
// packw: Wcat (512x512) -> B-fragment order
// fold: fold priv copies -> dis, cnt; allocate off via wave-agg atomic; curb
__global__ __launch_bounds__(512) void k_mid(
    const float* __restrict__ x, const float* __restrict__ h,
    const float* __restrict__ Wx, const float* __restrict__ Wh,
    unsigned int* __restrict__ xw, unsigned int* __restrict__ hw,
    unsigned short* __restrict__ Abf, unsigned short* __restrict__ Wbf,
    int* __restrict__ flagpart,
    const float* __restrict__ deg_priv, const unsigned short* __restrict__ cnt_priv,
    float* __restrict__ dis, int* __restrict__ cnt, int* __restrict__ off,
    int* __restrict__ curb, int* __restrict__ cursor,
    int n16, int n, int cvb) {

    const int bid = blockIdx.x;
    const int tid = threadIdx.x;
    const int lane = tid & 63;

    if (bid < cvb) {
        // ---------------- cvt section ----------------
        int t = bid * 512 + tid;
        bool nz = false;
        if (t < n16) {
            int r = t >> 4, o = t & 15;
            int slot = ((r & 15) + 16 * (o & 3)) * 8;
            size_t fb = ((size_t)(r >> 4) * 16) * 512;

            const float4* xp = reinterpret_cast<const float4*>(x) + (size_t)t * 2;
            float4 a = xp[0], bq = xp[1];
            uint4 ox;
            ox.x = pack2bf(a.x, a.y);   ox.y = pack2bf(a.z, a.w);
            ox.z = pack2bf(bq.x, bq.y); ox.w = pack2bf(bq.z, bq.w);
            reinterpret_cast<uint4*>(xw)[t] = ox;
            *reinterpret_cast<uint4*>(Abf + fb + (size_t)(o >> 2) * 512 + slot) = ox;

            const float4* hp = reinterpret_cast<const float4*>(h) + (size_t)t * 2;
            float4 hc = hp[0], hd = hp[1];
            nz = (hc.x != 0.f) | (hc.y != 0.f) | (hc.z != 0.f) | (hc.w != 0.f) |
                 (hd.x != 0.f) | (hd.y != 0.f) | (hd.z != 0.f) | (hd.w != 0.f);
            uint4 oh;
            oh.x = pack2bf(hc.x, hc.y); oh.y = pack2bf(hc.z, hc.w);
            oh.z = pack2bf(hd.x, hd.y); oh.w = pack2bf(hd.z, hd.w);
            reinterpret_cast<uint4*>(hw)[t] = oh;
            *reinterpret_cast<uint4*>(Abf + fb + (size_t)(8 + (o >> 2)) * 512 + slot) = oh;
        }
        __shared__ int fsh;
        if (tid == 0) fsh = 0;
        __syncthreads();
        unsigned long long m = __ballot(nz);
        if (lane == 0 && m) atomicOr(&fsh, 1);
        __syncthreads();
        if (tid == 0) flagpart[bid] = fsh;
        return;
    }

    if (bid < cvb + 64) {
        // ---------------- pack_w section ----------------
        int frag = (bid - cvb) * 8 + (tid >> 6);   // 0..511
        int cb = frag >> 4, kb = frag & 15;
        int col = cb * 16 + (lane & 15);
        int k0  = kb * 32 + (lane >> 4) * 8;

        int sel  = k0 >> 7;                // 0..3 : Wx0, Wx1, Wh0, Wh1
        int g    = col >> 7;
        int j    = col & (FD - 1);
        const float* Wb = (sel < 2) ? Wx : Wh;
        const float* p = Wb + (((size_t)g * 2 + (sel & 1)) * FD + (k0 & (FD - 1))) * FD + j;

        unsigned short outv[8];
        #pragma unroll
        for (int i = 0; i < 8; ++i) outv[i] = f2bf(p[(size_t)i * FD]);
        *reinterpret_cast<uint4*>(Wbf + (size_t)frag * 512 + lane * 8) =
            *reinterpret_cast<uint4*>(outv);
        return;
    }

    // ---------------- fold section ----------------
    int d = (bid - cvb - 64) * 512 + tid;
    int ct = 0;
    if (d < n) {
        float s = 0.f;
        #pragma unroll 4
        for (int b = 0; b < NB; ++b) {
            s  += deg_priv[(size_t)b * n + d];
            ct += (int)cnt_priv[(size_t)b * n + d];
        }
        dis[d] = (s > 0.0f) ? rsqrtf(fmaxf(s, 1e-12f)) : 0.0f;
        cnt[d] = ct;
    }

    // wave-aggregated offset allocation (CSR regions need not be d-monotonic)
    int s_incl = ct;
    #pragma unroll
    for (int o = 1; o < 64; o <<= 1) {
        int t2 = __shfl_up(s_incl, o);
        if (lane >= o) s_incl += t2;
    }
    int wtotal = __shfl(s_incl, 63);
    int base = 0;
    if (lane == 0) base = atomicAdd(cursor, wtotal);
    base = __shfl(base, 0);

    if (d < n) {
        int my0 = base + s_incl - ct;
        off[d] = my0;
        int run = my0;
        #pragma unroll 4
        for (int b = 0; b < NB; ++b) {
            curb[(size_t)b * n + d] = run;
            run += (int)cnt_priv[(size_t)b * n + d];   // L2-hot re-read
        }
    }
}

// ---- Kernel 3: bucket fill; cursor row staged in LDS (coalesced), then
//      LDS atomic allocation; block 0 also folds hflag OR. ----
__global__ __launch_bounds__(512) void k_fill_lds(
    const float* __restrict__ ew, const int* __restrict__ src,
    const int* __restrict__ dst, const float* __restrict__ dis,
    const int* __restrict__ curb, int2* __restrict__ epk,
    const int* __restrict__ flagpart, int* __restrict__ hflag,
    int E, int n, int ech, int cvb) {

    __shared__ int curL[NMAX];

    const int b = blockIdx.x;
    if (b == 0) {
        // hflag zeroed by k_hist (previous dispatch); OR the cvt flag parts.
        int fl = 0;
        for (int i = threadIdx.x; i < cvb; i += 512) fl |= flagpart[i];
        unsigned long long m = __ballot(fl != 0);
        if ((threadIdx.x & 63) == 0 && m) atomicOr(hflag, 1);
    }

    const int* crow = curb + (size_t)b * n;
    for (int i = threadIdx.x; i < n; i += 512) curL[i] = crow[i];
    __syncthreads();

    const int e0 = b * ech, e1 = min(e0 + ech, E);
    for (int e = e0 + (int)threadIdx.x; e < e1; e += 512) {
        int d = dst[e];
        int s = src[e];
        float w = -dis[s] * ew[e] * dis[d];
        int p = atomicAdd(&curL[d], 1);
        epk[p] = make_int2(s, __builtin_bit_cast(int, w));
    }
}

// ---- Kernel 4: gather -> writes tx/th A-fragments (kb 4-7, 12-15) directly
__global__ __launch_bounds__(256) void k_gather_bf(
    const unsigned int* __restrict__ xw, const unsigned int* __restrict__ hw,
    const int* __restrict__ off, const int* __restrict__ cntv,
    const int2* __restrict__ epk, const int* __restrict__ hflag,
    unsigned short* __restrict__ Abf, int n) {

    int d    = blockIdx.x * 4 + (threadIdx.x >> 6);
    int lane = threadIdx.x & 63;
    if (d >= n) return;
    const bool hasH = (*hflag) != 0;

    int p0 = off[d], p1 = p0 + cntv[d];
    float ax0 = 0.f, ax1 = 0.f, ah0 = 0.f, ah1 = 0.f;

    if (!hasH) {
        for (int base = p0; base < p1; base += 64) {
            int cnt = min(64, p1 - base);
            int2 my = make_int2(0, 0);
            if (lane < cnt) my = epk[base + lane];
            int   sm = my.x;
            float wm = __builtin_bit_cast(float, my.y);
            int k = 0;
            for (; k + 4 <= cnt; k += 4) {
                int   s0 = __shfl(sm, k),     s1 = __shfl(sm, k + 1);
                int   s2 = __shfl(sm, k + 2), s3 = __shfl(sm, k + 3);
                float w0 = __shfl(wm, k),     w1 = __shfl(wm, k + 1);
                float w2 = __shfl(wm, k + 2), w3 = __shfl(wm, k + 3);
                unsigned int u0 = xw[s0 * 64 + lane];
                unsigned int u1 = xw[s1 * 64 + lane];
                unsigned int u2 = xw[s2 * 64 + lane];
                unsigned int u3 = xw[s3 * 64 + lane];
                ax0 = fmaf(w0, bflo(u0), ax0); ax1 = fmaf(w0, bfhi(u0), ax1);
                ax0 = fmaf(w1, bflo(u1), ax0); ax1 = fmaf(w1, bfhi(u1), ax1);
                ax0 = fmaf(w2, bflo(u2), ax0); ax1 = fmaf(w2, bfhi(u2), ax1);
                ax0 = fmaf(w3, bflo(u3), ax0); ax1 = fmaf(w3, bfhi(u3), ax1);
            }
            for (; k < cnt; ++k) {
                int s = __shfl(sm, k);
                float w = __shfl(wm, k);
                unsigned int u = xw[s * 64 + lane];
                ax0 = fmaf(w, bflo(u), ax0); ax1 = fmaf(w, bfhi(u), ax1);
            }
        }
    } else {
        for (int base = p0; base < p1; base += 64) {
            int cnt = min(64, p1 - base);
            int2 my = make_int2(0, 0);
            if (lane < cnt) my = epk[base + lane];
            int   sm = my.x;
            float wm = __builtin_bit_cast(float, my.y);
            int k = 0;
            for (; k + 2 <= cnt; k += 2) {
                int   s0 = __shfl(sm, k), s1 = __shfl(sm, k + 1);
                float w0 = __shfl(wm, k), w1 = __shfl(wm, k + 1);
                unsigned int u0 = xw[s0 * 64 + lane];
                unsigned int v0 = hw[s0 * 64 + lane];
                unsigned int u1 = xw[s1 * 64 + lane];
                unsigned int v1 = hw[s1 * 64 + lane];
                ax0 = fmaf(w0, bflo(u0), ax0); ax1 = fmaf(w0, bfhi(u0), ax1);
                ah0 = fmaf(w0, bflo(v0), ah0); ah1 = fmaf(w0, bfhi(v0), ah1);
                ax0 = fmaf(w1, bflo(u1), ax0); ax1 = fmaf(w1, bfhi(u1), ax1);
                ah0 = fmaf(w1, bflo(v1), ah0); ah1 = fmaf(w1, bfhi(v1), ah1);
            }
            for (; k < cnt; ++k) {
                int s = __shfl(sm, k);
                float w = __shfl(wm, k);
                unsigned int u = xw[s * 64 + lane];
                unsigned int v = hw[s * 64 + lane];
                ax0 = fmaf(w, bflo(u), ax0); ax1 = fmaf(w, bfhi(u), ax1);
                ah0 = fmaf(w, bflo(v), ah0); ah1 = fmaf(w, bfhi(v), ah1);
            }
        }
    }

    unsigned int* Au = (unsigned int*)Abf;
    size_t fragT = (size_t)(d >> 4) * 16 + 4 + (lane >> 4);
    int slotu = ((d & 15) + 16 * ((lane >> 2) & 3)) * 4 + (lane & 3);
    Au[fragT * 256 + slotu] = pack2bf(ax0, ax1);
    if (hasH) Au[(fragT + 8) * 256 + slotu] = pack2bf(ah0, ah1);
}

// ---- Kernel 5: fused MFMA GEMM + LSTM epilogue ----
// Block: 8 waves own one 64-row tile (A-frags fetched once per tile).
// Wave jj: 64 rows x {16 cols of each of the 4 gates}: col-frags cf = g*8+jj.
__global__ __launch_bounds__(512) void k_gemm_lstm(
    const unsigned short* __restrict__ Abf, const unsigned short* __restrict__ Wbf,
    const int* __restrict__ hflag,
    const float* __restrict__ c, const float* __restrict__ bias,
    const float* __restrict__ wc, float* __restrict__ out, int n) {

    int rt   = blockIdx.x;            // row tile (64 rows)
    int jj   = threadIdx.x >> 6;      // 16-col slice within each gate (0..7)
    int lane = threadIdx.x & 63;
    const int kbmax = (*hflag) ? 16 : 8;

    f32x4 acc[4][4];
    #pragma unroll
    for (int mi = 0; mi < 4; ++mi)
        #pragma unroll
        for (int g = 0; g < 4; ++g)
            acc[mi][g] = (f32x4)0.0f;

    const size_t aoff = ((size_t)(rt * 4) * 16) * 512 + lane * 8;

    for (int kb = 0; kb < kbmax; ++kb) {
        bf16x8 a[4], b[4];
        #pragma unroll
        for (int mi = 0; mi < 4; ++mi)
            a[mi] = *reinterpret_cast<const bf16x8*>(Abf + aoff + (size_t)(mi * 16 + kb) * 512);
        #pragma unroll
        for (int g = 0; g < 4; ++g)
            b[g] = *reinterpret_cast<const bf16x8*>(
                Wbf + ((size_t)(g * 8 + jj) * 16 + kb) * 512 + lane * 8);
        #pragma unroll
        for (int mi = 0; mi < 4; ++mi)
            #pragma unroll
            for (int g = 0; g < 4; ++g)
                acc[mi][g] = __builtin_amdgcn_mfma_f32_16x16x32_bf16(
                                 a[mi], b[g], acc[mi][g], 0, 0, 0);
    }

    const int r0   = rt * 64;
    const int col  = jj * 16 + (lane & 15);
    const size_t NH = (size_t)n * FD;
    const float wc0 = wc[0 * FD + col], wc1 = wc[1 * FD + col], wc2 = wc[2 * FD + col];
    const float b0  = bias[0 * FD + col], b1 = bias[1 * FD + col];
    const float b2  = bias[2 * FD + col], b3 = bias[3 * FD + col];

    #pragma unroll
    for (int mi = 0; mi < 4; ++mi) {
        #pragma unroll
        for (int q = 0; q < 4; ++q) {
            int r = r0 + mi * 16 + (lane >> 4) * 4 + q;
            if (r >= n) continue;
            float cv = c[(size_t)r * FD + col];
            float gi = acc[mi][0][q] + wc0 * cv + b0;
            float gf = acc[mi][1][q] + wc1 * cv + b1;
            float gg = acc[mi][2][q] + b2;
            float iv = sigmoidf_(gi);
            float fv = sigmoidf_(gf);
            float cn = fv * cv + iv * tanhf(gg);
            float go = acc[mi][3][q] + wc2 * cn + b3;
            float hn = sigmoidf_(go) * tanhf(cn);
            size_t o = (size_t)r * FD + col;
            out[o]          = hn;
            out[NH + o]     = hn;
            out[2 * NH + o] = cn;
        }
    }
}

extern "C" void kernel_launch(void* const* d_in, const int* in_sizes, int n_in,
                              void* d_out, int out_size, void* d_ws, size_t ws_size,
                              hipStream_t stream) {
    const float* x   = (const float*)d_in[0];
    const float* ew  = (const float*)d_in[1];
    const float* h   = (const float*)d_in[2];
    const float* c   = (const float*)d_in[3];
    const float* Wx  = (const float*)d_in[4];
    const float* Wh  = (const float*)d_in[5];
    const float* b   = (const float*)d_in[6];
    const float* wc  = (const float*)d_in[7];
    const int*   src = (const int*)d_in[8];
    const int*   dst = (const int*)d_in[9];

    const int n = in_sizes[0] / FD;   // 20000  (<= NMAX)
    const int E = in_sizes[1];        // 640000

    const int Mpad = (n + 63) & ~63;              // 20032
    const int ech  = (E + NB - 1) / NB;           // 5000
    const int n16  = n * 16;
    const int cvb  = (n16 + 511) / 512;           // cvt section blocks (625)
    const int npf  = (n + 511) / 512;             // fold section blocks (40)

    // ---- workspace layout (all regions disjoint; ws is 256MB) ----
    float* dis      = (float*)d_ws;                        // n
    int*   cnt      = (int*)(dis + n);                     // n
    int*   off      = cnt + n;                             // n+4
    int*   hflag    = off + n + 4;                         // 4
    int*   cursor   = hflag + 4;                           // 4
    int*   flagpart = cursor + 4;                          // 1280 (pad)
    int2*  epk      = (int2*)(flagpart + 1280);            // E
    unsigned int* xw = (unsigned int*)(epk + E);           // n*64
    unsigned int* hw = xw + (size_t)n * 64;                // n*64
    unsigned short* Abf = (unsigned short*)(hw + (size_t)n * 64);  // Mpad*512
    unsigned short* Wbf = Abf + (size_t)Mpad * 512;        // 512*512
    int*   curb     = (int*)(Wbf + 512 * 512);             // NB*n
    float* deg_priv = (float*)(curb + (size_t)NB * n);     // NB*n
    unsigned short* cnt_priv = (unsigned short*)(deg_priv + (size_t)NB * n); // NB*n

    k_hist_lds<<<NB, 512, 0, stream>>>(ew, src, dst, deg_priv, cnt_priv,
                                       cursor, hflag, E, n, ech);
    k_mid<<<cvb + 64 + npf, 512, 0, stream>>>(x, h, Wx, Wh, xw, hw, Abf, Wbf,
                                              flagpart, deg_priv, cnt_priv,
                                              dis, cnt, off, curb, cursor,
                                              n16, n, cvb);
    k_fill_lds<<<NB, 512, 0, stream>>>(ew, src, dst, dis, curb, epk,
                                       flagpart, hflag, E, n, ech, cvb);
    k_gather_bf<<<(n + 3) / 4, 256, 0, stream>>>(xw, hw, off, cnt, epk, hflag, Abf, n);

    k_gemm_lstm<<<Mpad / 64, 512, 0, stream>>>(Abf, Wbf, hflag, c, b, wc,
                                               (float*)d_out, n);
}

// Round 14
// 108.770 us; speedup vs baseline: 1.9220x; 1.0424x over previous
//
#include <hip/hip_runtime.h>
#include <math.h>

#define FD 128
#define GATES 4
#define NB   128           // edge chunks (per-chunk private histograms)
#define NMAX 20032         // max node count supported by LDS-resident hist/fill

typedef __attribute__((ext_vector_type(8))) short bf16x8;
typedef __attribute__((ext_vector_type(4))) float f32x4;

__device__ __forceinline__ float sigmoidf_(float v) {
    return 1.0f / (1.0f + expf(-v));
}

__device__ __forceinline__ unsigned short f2bf(float f) {
    unsigned int u = __builtin_bit_cast(unsigned int, f);
    u += 0x7fffu + ((u >> 16) & 1u);           // RNE (finite values)
    return (unsigned short)(u >> 16);
}
__device__ __forceinline__ float bflo(unsigned int u) {
    return __builtin_bit_cast(float, u << 16);
}
__device__ __forceinline__ float bfhi(unsigned int u) {
    return __builtin_bit_cast(float, u & 0xffff0000u);
}
__device__ __forceinline__ unsigned int pack2bf(float lo, float hi) {
    return (unsigned int)f2bf(lo) | ((unsigned int)f2bf(hi) << 16);
}

// ---- Kernel 1: hist (blocks 0..NB-1) || cvt (next cvb blocks) || pack_w (64)
// Sections are data-independent; no cross-section sync needed.
// hist: per-chunk LDS histogram (deg f32, dst-count packed 2xu16).
// cvt:  x,h -> bf16 rows + A-frags kb 0-3/8-11 + per-block h-flag parts.
// packw: Wcat (512x512) -> B-fragment order.
__global__ __launch_bounds__(512) void k_front(
    const float* __restrict__ ew, const int* __restrict__ src,
    const int* __restrict__ dst,
    float* __restrict__ deg_priv, unsigned short* __restrict__ cnt_priv,
    int* __restrict__ cursor, int* __restrict__ hflag,
    const float* __restrict__ x, const float* __restrict__ h,
    const float* __restrict__ Wx, const float* __restrict__ Wh,
    unsigned int* __restrict__ xw, unsigned int* __restrict__ hw,
    unsigned short* __restrict__ Abf, unsigned short* __restrict__ Wbf,
    int* __restrict__ flagpart,
    int E, int n, int ech, int n16, int cvb) {

    __shared__ float        degL[NMAX];
    __shared__ unsigned int cntP[NMAX / 2];

    const int bid  = blockIdx.x;
    const int tid  = threadIdx.x;
    const int lane = tid & 63;

    if (bid < NB) {
        // ---------------- hist section ----------------
        if (bid == 0 && tid == 0) { cursor[0] = 0; hflag[0] = 0; }

        const int b  = bid;
        const int nh = (n + 1) >> 1;
        for (int i = tid; i < n;  i += 512) degL[i] = 0.f;
        for (int i = tid; i < nh; i += 512) cntP[i] = 0u;
        __syncthreads();

        const int e0 = b * ech, e1 = min(e0 + ech, E);
        for (int e = e0 + tid; e < e1; e += 512) {
            int s = src[e], d = dst[e];
            atomicAdd(&degL[s], ew[e]);
            atomicAdd(&cntP[d >> 1], (d & 1) ? 0x10000u : 1u);
        }
        __syncthreads();

        float*          dp = deg_priv + (size_t)b * n;
        unsigned short* cp = cnt_priv + (size_t)b * n;
        for (int i = tid; i < n; i += 512) dp[i] = degL[i];
        for (int i = tid; i < n; i += 512) {
            unsigned int v = cntP[i >> 1];
            cp[i] = (unsigned short)((i & 1) ? (v >> 16) : (v & 0xffffu));
        }
        return;
    }

    if (bid < NB + cvb) {
        // ---------------- cvt section ----------------
        int t = (bid - NB) * 512 + tid;
        bool nz = false;
        if (t < n16) {
            int r = t >> 4, o = t & 15;
            int slot = ((r & 15) + 16 * (o & 3)) * 8;
            size_t fb = ((size_t)(r >> 4) * 16) * 512;

            const float4* xp = reinterpret_cast<const float4*>(x) + (size_t)t * 2;
            float4 a = xp[0], bq = xp[1];
            uint4 ox;
            ox.x = pack2bf(a.x, a.y);   ox.y = pack2bf(a.z, a.w);
            ox.z = pack2bf(bq.x, bq.y); ox.w = pack2bf(bq.z, bq.w);
            reinterpret_cast<uint4*>(xw)[t] = ox;
            *reinterpret_cast<uint4*>(Abf + fb + (size_t)(o >> 2) * 512 + slot) = ox;

            const float4* hp = reinterpret_cast<const float4*>(h) + (size_t)t * 2;
            float4 hc = hp[0], hd = hp[1];
            nz = (hc.x != 0.f) | (hc.y != 0.f) | (hc.z != 0.f) | (hc.w != 0.f) |
                 (hd.x != 0.f) | (hd.y != 0.f) | (hd.z != 0.f) | (hd.w != 0.f);
            uint4 oh;
            oh.x = pack2bf(hc.x, hc.y); oh.y = pack2bf(hc.z, hc.w);
            oh.z = pack2bf(hd.x, hd.y); oh.w = pack2bf(hd.z, hd.w);
            reinterpret_cast<uint4*>(hw)[t] = oh;
            *reinterpret_cast<uint4*>(Abf + fb + (size_t)(8 + (o >> 2)) * 512 + slot) = oh;
        }
        __shared__ int fsh;
        if (tid == 0) fsh = 0;
        __syncthreads();
        unsigned long long m = __ballot(nz);
        if (lane == 0 && m) atomicOr(&fsh, 1);
        __syncthreads();
        if (tid == 0) flagpart[bid - NB] = fsh;
        return;
    }

    // ---------------- pack_w section ----------------
    {
        int frag = (bid - NB - cvb) * 8 + (tid >> 6);   // 0..511
        int cb = frag >> 4, kb = frag & 15;
        int col = cb * 16 + (lane & 15);
        int k0  = kb * 32 + (lane >> 4) * 8;

        int sel  = k0 >> 7;                // 0..3 : Wx0, Wx1, Wh0, Wh1
        int g    = col >> 7;
        int j    = col & (FD - 1);
        const float* Wb = (sel < 2) ? Wx : Wh;
        const float* p = Wb + (((size_t)g * 2 + (sel & 1)) * FD + (k0 & (FD - 1))) * FD + j;

        unsigned short outv[8];
        #pragma unroll
        for (int i = 0; i < 8; ++i) outv[i] = f2bf(p[(size_t)i * FD]);
        *reinterpret_cast<uint4*>(Wbf + (size_t)frag * 512 + lane * 8) =
            *reinterpret_cast<uint4*>(outv);
    }
}

// ---- Kernel 2: fold priv copies -> dis, cnt; allocate off (wave-agg atomic);
//      write per-chunk cursors curb. ----
__global__ __launch_bounds__(512) void k_fold(
    const float* __restrict__ deg_priv, const unsigned short* __restrict__ cnt_priv,
    float* __restrict__ dis, int* __restrict__ cnt, int* __restrict__ off,
    int* __restrict__ curb, int* __restrict__ cursor, int n) {

    int d = blockIdx.x * 512 + threadIdx.x;
    int lane = threadIdx.x & 63;
    int ct = 0;
    if (d < n) {
        float s = 0.f;
        #pragma unroll 4
        for (int b = 0; b < NB; ++b) {
            s  += deg_priv[(size_t)b * n + d];
            ct += (int)cnt_priv[(size_t)b * n + d];
        }
        dis[d] = (s > 0.0f) ? rsqrtf(fmaxf(s, 1e-12f)) : 0.0f;
        cnt[d] = ct;
    }

    // wave-aggregated offset allocation (CSR regions need not be d-monotonic)
    int s_incl = ct;
    #pragma unroll
    for (int o = 1; o < 64; o <<= 1) {
        int t2 = __shfl_up(s_incl, o);
        if (lane >= o) s_incl += t2;
    }
    int wtotal = __shfl(s_incl, 63);
    int base = 0;
    if (lane == 0) base = atomicAdd(cursor, wtotal);
    base = __shfl(base, 0);

    if (d < n) {
        int my0 = base + s_incl - ct;
        off[d] = my0;
        int run = my0;
        #pragma unroll 4
        for (int b = 0; b < NB; ++b) {
            curb[(size_t)b * n + d] = run;
            run += (int)cnt_priv[(size_t)b * n + d];   // L2-hot re-read
        }
    }
}

// ---- Kernel 3: bucket fill; cursor row staged in LDS (coalesced), then
//      LDS atomic allocation; block 0 also folds hflag OR. ----
__global__ __launch_bounds__(512) void k_fill_lds(
    const float* __restrict__ ew, const int* __restrict__ src,
    const int* __restrict__ dst, const float* __restrict__ dis,
    const int* __restrict__ curb, int2* __restrict__ epk,
    const int* __restrict__ flagpart, int* __restrict__ hflag,
    int E, int n, int ech, int cvb) {

    __shared__ int curL[NMAX];

    const int b = blockIdx.x;
    if (b == 0) {
        // hflag zeroed by k_front (previous dispatch); OR the cvt flag parts.
        int fl = 0;
        for (int i = threadIdx.x; i < cvb; i += 512) fl |= flagpart[i];
        unsigned long long m = __ballot(fl != 0);
        if ((threadIdx.x & 63) == 0 && m) atomicOr(hflag, 1);
    }

    const int* crow = curb + (size_t)b * n;
    for (int i = threadIdx.x; i < n; i += 512) curL[i] = crow[i];
    __syncthreads();

    const int e0 = b * ech, e1 = min(e0 + ech, E);
    for (int e = e0 + (int)threadIdx.x; e < e1; e += 512) {
        int d = dst[e];
        int s = src[e];
        float w = -dis[s] * ew[e] * dis[d];
        int p = atomicAdd(&curL[d], 1);
        epk[p] = make_int2(s, __builtin_bit_cast(int, w));
    }
}

// ---- Kernel 4: gather -> writes tx/th A-fragments (kb 4-7, 12-15) directly
__global__ __launch_bounds__(256) void k_gather_bf(
    const unsigned int* __restrict__ xw, const unsigned int* __restrict__ hw,
    const int* __restrict__ off, const int* __restrict__ cntv,
    const int2* __restrict__ epk, const int* __restrict__ hflag,
    unsigned short* __restrict__ Abf, int n) {

    int d    = blockIdx.x * 4 + (threadIdx.x >> 6);
    int lane = threadIdx.x & 63;
    if (d >= n) return;
    const bool hasH = (*hflag) != 0;

    int p0 = off[d], p1 = p0 + cntv[d];
    float ax0 = 0.f, ax1 = 0.f, ah0 = 0.f, ah1 = 0.f;

    if (!hasH) {
        for (int base = p0; base < p1; base += 64) {
            int cnt = min(64, p1 - base);
            int2 my = make_int2(0, 0);
            if (lane < cnt) my = epk[base + lane];
            int   sm = my.x;
            float wm = __builtin_bit_cast(float, my.y);
            int k = 0;
            for (; k + 4 <= cnt; k += 4) {
                int   s0 = __shfl(sm, k),     s1 = __shfl(sm, k + 1);
                int   s2 = __shfl(sm, k + 2), s3 = __shfl(sm, k + 3);
                float w0 = __shfl(wm, k),     w1 = __shfl(wm, k + 1);
                float w2 = __shfl(wm, k + 2), w3 = __shfl(wm, k + 3);
                unsigned int u0 = xw[s0 * 64 + lane];
                unsigned int u1 = xw[s1 * 64 + lane];
                unsigned int u2 = xw[s2 * 64 + lane];
                unsigned int u3 = xw[s3 * 64 + lane];
                ax0 = fmaf(w0, bflo(u0), ax0); ax1 = fmaf(w0, bfhi(u0), ax1);
                ax0 = fmaf(w1, bflo(u1), ax0); ax1 = fmaf(w1, bfhi(u1), ax1);
                ax0 = fmaf(w2, bflo(u2), ax0); ax1 = fmaf(w2, bfhi(u2), ax1);
                ax0 = fmaf(w3, bflo(u3), ax0); ax1 = fmaf(w3, bfhi(u3), ax1);
            }
            for (; k < cnt; ++k) {
                int s = __shfl(sm, k);
                float w = __shfl(wm, k);
                unsigned int u = xw[s * 64 + lane];
                ax0 = fmaf(w, bflo(u), ax0); ax1 = fmaf(w, bfhi(u), ax1);
            }
        }
    } else {
        for (int base = p0; base < p1; base += 64) {
            int cnt = min(64, p1 - base);
            int2 my = make_int2(0, 0);
            if (lane < cnt) my = epk[base + lane];
            int   sm = my.x;
            float wm = __builtin_bit_cast(float, my.y);
            int k = 0;
            for (; k + 2 <= cnt; k += 2) {
                int   s0 = __shfl(sm, k), s1 = __shfl(sm, k + 1);
                float w0 = __shfl(wm, k), w1 = __shfl(wm, k + 1);
                unsigned int u0 = xw[s0 * 64 + lane];
                unsigned int v0 = hw[s0 * 64 + lane];
                unsigned int u1 = xw[s1 * 64 + lane];
                unsigned int v1 = hw[s1 * 64 + lane];
                ax0 = fmaf(w0, bflo(u0), ax0); ax1 = fmaf(w0, bfhi(u0), ax1);
                ah0 = fmaf(w0, bflo(v0), ah0); ah1 = fmaf(w0, bfhi(v0), ah1);
                ax0 = fmaf(w1, bflo(u1), ax0); ax1 = fmaf(w1, bfhi(u1), ax1);
                ah0 = fmaf(w1, bflo(v1), ah0); ah1 = fmaf(w1, bfhi(v1), ah1);
            }
            for (; k < cnt; ++k) {
                int s = __shfl(sm, k);
                float w = __shfl(wm, k);
                unsigned int u = xw[s * 64 + lane];
                unsigned int v = hw[s * 64 + lane];
                ax0 = fmaf(w, bflo(u), ax0); ax1 = fmaf(w, bfhi(u), ax1);
                ah0 = fmaf(w, bflo(v), ah0); ah1 = fmaf(w, bfhi(v), ah1);
            }
        }
    }

    unsigned int* Au = (unsigned int*)Abf;
    size_t fragT = (size_t)(d >> 4) * 16 + 4 + (lane >> 4);
    int slotu = ((d & 15) + 16 * ((lane >> 2) & 3)) * 4 + (lane & 3);
    Au[fragT * 256 + slotu] = pack2bf(ax0, ax1);
    if (hasH) Au[(fragT + 8) * 256 + slotu] = pack2bf(ah0, ah1);
}

// ---- Kernel 5: fused MFMA GEMM + LSTM epilogue ----
// Block: 8 waves own one 64-row tile (A-frags fetched once per tile).
// Wave jj: 64 rows x {16 cols of each of the 4 gates}: col-frags cf = g*8+jj.
__global__ __launch_bounds__(512) void k_gemm_lstm(
    const unsigned short* __restrict__ Abf, const unsigned short* __restrict__ Wbf,
    const int* __restrict__ hflag,
    const float* __restrict__ c, const float* __restrict__ bias,
    const float* __restrict__ wc, float* __restrict__ out, int n) {

    int rt   = blockIdx.x;            // row tile (64 rows)
    int jj   = threadIdx.x >> 6;      // 16-col slice within each gate (0..7)
    int lane = threadIdx.x & 63;
    const int kbmax = (*hflag) ? 16 : 8;

    f32x4 acc[4][4];
    #pragma unroll
    for (int mi = 0; mi < 4; ++mi)
        #pragma unroll
        for (int g = 0; g < 4; ++g)
            acc[mi][g] = (f32x4)0.0f;

    const size_t aoff = ((size_t)(rt * 4) * 16) * 512 + lane * 8;

    for (int kb = 0; kb < kbmax; ++kb) {
        bf16x8 a[4], b[4];
        #pragma unroll
        for (int mi = 0; mi < 4; ++mi)
            a[mi] = *reinterpret_cast<const bf16x8*>(Abf + aoff + (size_t)(mi * 16 + kb) * 512);
        #pragma unroll
        for (int g = 0; g < 4; ++g)
            b[g] = *reinterpret_cast<const bf16x8*>(
                Wbf + ((size_t)(g * 8 + jj) * 16 + kb) * 512 + lane * 8);
        #pragma unroll
        for (int mi = 0; mi < 4; ++mi)
            #pragma unroll
            for (int g = 0; g < 4; ++g)
                acc[mi][g] = __builtin_amdgcn_mfma_f32_16x16x32_bf16(
                                 a[mi], b[g], acc[mi][g], 0, 0, 0);
    }

    const int r0   = rt * 64;
    const int col  = jj * 16 + (lane & 15);
    const size_t NH = (size_t)n * FD;
    const float wc0 = wc[0 * FD + col], wc1 = wc[1 * FD + col], wc2 = wc[2 * FD + col];
    const float b0  = bias[0 * FD + col], b1 = bias[1 * FD + col];
    const float b2  = bias[2 * FD + col], b3 = bias[3 * FD + col];

    #pragma unroll
    for (int mi = 0; mi < 4; ++mi) {
        #pragma unroll
        for (int q = 0; q < 4; ++q) {
            int r = r0 + mi * 16 + (lane >> 4) * 4 + q;
            if (r >= n) continue;
            float cv = c[(size_t)r * FD + col];
            float gi = acc[mi][0][q] + wc0 * cv + b0;
            float gf = acc[mi][1][q] + wc1 * cv + b1;
            float gg = acc[mi][2][q] + b2;
            float iv = sigmoidf_(gi);
            float fv = sigmoidf_(gf);
            float cn = fv * cv + iv * tanhf(gg);
            float go = acc[mi][3][q] + wc2 * cn + b3;
            float hn = sigmoidf_(go) * tanhf(cn);
            size_t o = (size_t)r * FD + col;
            out[o]          = hn;
            out[NH + o]     = hn;
            out[2 * NH + o] = cn;
        }
    }
}

extern "C" void kernel_launch(void* const* d_in, const int* in_sizes, int n_in,
                              void* d_out, int out_size, void* d_ws, size_t ws_size,
                              hipStream_t stream) {
    const float* x   = (const float*)d_in[0];
    const float* ew  = (const float*)d_in[1];
    const float* h   = (const float*)d_in[2];
    const float* c   = (const float*)d_in[3];
    const float* Wx  = (const float*)d_in[4];
    const float* Wh  = (const float*)d_in[5];
    const float* b   = (const float*)d_in[6];
    const float* wc  = (const float*)d_in[7];
    const int*   src = (const int*)d_in[8];
    const int*   dst = (const int*)d_in[9];

    const int n = in_sizes[0] / FD;   // 20000  (<= NMAX)
    const int E = in_sizes[1];        // 640000

    const int Mpad = (n + 63) & ~63;              // 20032
    const int ech  = (E + NB - 1) / NB;           // 5000
    const int n16  = n * 16;
    const int cvb  = (n16 + 511) / 512;           // cvt section blocks (625)
    const int npf  = (n + 511) / 512;             // fold blocks (40)

    // ---- workspace layout (all regions disjoint; ws is 256MB) ----
    float* dis      = (float*)d_ws;                        // n
    int*   cnt      = (int*)(dis + n);                     // n
    int*   off      = cnt + n;                             // n+4
    int*   hflag    = off + n + 4;                         // 4
    int*   cursor   = hflag + 4;                           // 4
    int*   flagpart = cursor + 4;                          // 1280 (pad)
    int2*  epk      = (int2*)(flagpart + 1280);            // E
    unsigned int* xw = (unsigned int*)(epk + E);           // n*64
    unsigned int* hw = xw + (size_t)n * 64;                // n*64
    unsigned short* Abf = (unsigned short*)(hw + (size_t)n * 64);  // Mpad*512
    unsigned short* Wbf = Abf + (size_t)Mpad * 512;        // 512*512
    int*   curb     = (int*)(Wbf + 512 * 512);             // NB*n
    float* deg_priv = (float*)(curb + (size_t)NB * n);     // NB*n
    unsigned short* cnt_priv = (unsigned short*)(deg_priv + (size_t)NB * n); // NB*n

    k_front<<<NB + cvb + 64, 512, 0, stream>>>(
        ew, src, dst, deg_priv, cnt_priv, cursor, hflag,
        x, h, Wx, Wh, xw, hw, Abf, Wbf, flagpart,
        E, n, ech, n16, cvb);
    k_fold<<<npf, 512, 0, stream>>>(deg_priv, cnt_priv, dis, cnt, off, curb,
                                    cursor, n);
    k_fill_lds<<<NB, 512, 0, stream>>>(ew, src, dst, dis, curb, epk,
                                       flagpart, hflag, E, n, ech, cvb);
    k_gather_bf<<<(n + 3) / 4, 256, 0, stream>>>(xw, hw, off, cnt, epk, hflag, Abf, n);

    k_gemm_lstm<<<Mpad / 64, 512, 0, stream>>>(Abf, Wbf, hflag, c, b, wc,
                                               (float*)d_out, n);
}

// Round 15
// 107.128 us; speedup vs baseline: 1.9514x; 1.0153x over previous
//
#include <hip/hip_runtime.h>
#include <math.h>

#define FD 128
#define GATES 4
#define NB   128           // edge chunks (per-chunk private histograms)
#define NRH  2             // hist node ranges (LDS = rs*6 B)
#define NRF  2             // fill node ranges (LDS = rs*4 B)
#define RSH_MAX 10016      // max nodes per hist range (~59 KB LDS)
#define RSF_MAX 10016      // max nodes per fill range (~40 KB LDS)
#define NMAX (RSH_MAX * 2) // max node count

typedef __attribute__((ext_vector_type(8))) short bf16x8;
typedef __attribute__((ext_vector_type(4))) float f32x4;

__device__ __forceinline__ float sigmoidf_(float v) {
    return 1.0f / (1.0f + expf(-v));
}

__device__ __forceinline__ unsigned short f2bf(float f) {
    unsigned int u = __builtin_bit_cast(unsigned int, f);
    u += 0x7fffu + ((u >> 16) & 1u);           // RNE (finite values)
    return (unsigned short)(u >> 16);
}
__device__ __forceinline__ float bflo(unsigned int u) {
    return __builtin_bit_cast(float, u << 16);
}
__device__ __forceinline__ float bfhi(unsigned int u) {
    return __builtin_bit_cast(float, u & 0xffff0000u);
}
__device__ __forceinline__ unsigned int pack2bf(float lo, float hi) {
    return (unsigned int)f2bf(lo) | ((unsigned int)f2bf(hi) << 16);
}

// ---- Kernel 1: hist (NB*NRH blocks) || cvt (cvb blocks) || pack_w (64) ----
// hist: per-(chunk, node-range) LDS histogram; ~59 KB LDS -> 2 blocks/CU, so
// cvt blocks co-reside at 16 waves/CU instead of 8.
__global__ __launch_bounds__(512) void k_front(
    const float* __restrict__ ew, const int* __restrict__ src,
    const int* __restrict__ dst,
    float* __restrict__ deg_priv, unsigned short* __restrict__ cnt_priv,
    int* __restrict__ cursor, int* __restrict__ hflag,
    const float* __restrict__ x, const float* __restrict__ h,
    const float* __restrict__ Wx, const float* __restrict__ Wh,
    unsigned int* __restrict__ xw, unsigned int* __restrict__ hw,
    unsigned short* __restrict__ Abf, unsigned short* __restrict__ Wbf,
    int* __restrict__ flagpart,
    int E, int n, int ech, int rs, int n16, int cvb) {

    __shared__ float        degL[RSH_MAX];
    __shared__ unsigned int cntP[RSH_MAX / 2];

    const int bid  = blockIdx.x;
    const int tid  = threadIdx.x;
    const int lane = tid & 63;
    const int NH_BLOCKS = NB * NRH;

    if (bid < NH_BLOCKS) {
        // ---------------- hist section ----------------
        if (bid == 0 && tid == 0) { cursor[0] = 0; hflag[0] = 0; }

        const int b    = bid & (NB - 1);
        const int r    = bid >> 7;            // NB==128
        const int base = r * rs;
        const int rse  = min(rs, n - base);
        const int nh   = (rse + 1) >> 1;

        for (int i = tid; i < rse; i += 512) degL[i] = 0.f;
        for (int i = tid; i < nh;  i += 512) cntP[i] = 0u;
        __syncthreads();

        const int e0 = b * ech, e1 = min(e0 + ech, E);
        for (int e = e0 + tid; e < e1; e += 512) {
            int s = src[e], d = dst[e];
            unsigned int rs_ = (unsigned int)(s - base);
            unsigned int rd_ = (unsigned int)(d - base);
            if (rs_ < (unsigned int)rse) atomicAdd(&degL[rs_], ew[e]);
            if (rd_ < (unsigned int)rse) atomicAdd(&cntP[rd_ >> 1], (rd_ & 1) ? 0x10000u : 1u);
        }
        __syncthreads();

        float*          dp = deg_priv + (size_t)b * n + base;
        unsigned short* cp = cnt_priv + (size_t)b * n + base;
        for (int i = tid; i < rse; i += 512) dp[i] = degL[i];
        for (int i = tid; i < rse; i += 512) {
            unsigned int v = cntP[i >> 1];
            cp[i] = (unsigned short)((i & 1) ? (v >> 16) : (v & 0xffffu));
        }
        return;
    }

    if (bid < NH_BLOCKS + cvb) {
        // ---------------- cvt section ----------------
        int t = (bid - NH_BLOCKS) * 512 + tid;
        bool nz = false;
        if (t < n16) {
            int r = t >> 4, o = t & 15;
            int slot = ((r & 15) + 16 * (o & 3)) * 8;
            size_t fb = ((size_t)(r >> 4) * 16) * 512;

            const float4* xp = reinterpret_cast<const float4*>(x) + (size_t)t * 2;
            float4 a = xp[0], bq = xp[1];
            uint4 ox;
            ox.x = pack2bf(a.x, a.y);   ox.y = pack2bf(a.z, a.w);
            ox.z = pack2bf(bq.x, bq.y); ox.w = pack2bf(bq.z, bq.w);
            reinterpret_cast<uint4*>(xw)[t] = ox;
            *reinterpret_cast<uint4*>(Abf + fb + (size_t)(o >> 2) * 512 + slot) = ox;

            const float4* hp = reinterpret_cast<const float4*>(h) + (size_t)t * 2;
            float4 hc = hp[0], hd = hp[1];
            nz = (hc.x != 0.f) | (hc.y != 0.f) | (hc.z != 0.f) | (hc.w != 0.f) |
                 (hd.x != 0.f) | (hd.y != 0.f) | (hd.z != 0.f) | (hd.w != 0.f);
            uint4 oh;
            oh.x = pack2bf(hc.x, hc.y); oh.y = pack2bf(hc.z, hc.w);
            oh.z = pack2bf(hd.x, hd.y); oh.w = pack2bf(hd.z, hd.w);
            reinterpret_cast<uint4*>(hw)[t] = oh;
            *reinterpret_cast<uint4*>(Abf + fb + (size_t)(8 + (o >> 2)) * 512 + slot) = oh;
        }
        __shared__ int fsh;
        if (tid == 0) fsh = 0;
        __syncthreads();
        unsigned long long m = __ballot(nz);
        if (lane == 0 && m) atomicOr(&fsh, 1);
        __syncthreads();
        if (tid == 0) flagpart[bid - NH_BLOCKS] = fsh;
        return;
    }

    // ---------------- pack_w section ----------------
    {
        int frag = (bid - NH_BLOCKS - cvb) * 8 + (tid >> 6);   // 0..511
        int cb = frag >> 4, kb = frag & 15;
        int col = cb * 16 + (lane & 15);
        int k0  = kb * 32 + (lane >> 4) * 8;

        int sel  = k0 >> 7;                // 0..3 : Wx0, Wx1, Wh0, Wh1
        int g    = col >> 7;
        int j    = col & (FD - 1);
        const float* Wb = (sel < 2) ? Wx : Wh;
        const float* p = Wb + (((size_t)g * 2 + (sel & 1)) * FD + (k0 & (FD - 1))) * FD + j;

        unsigned short outv[8];
        #pragma unroll
        for (int i = 0; i < 8; ++i) outv[i] = f2bf(p[(size_t)i * FD]);
        *reinterpret_cast<uint4*>(Wbf + (size_t)frag * 512 + lane * 8) =
            *reinterpret_cast<uint4*>(outv);
    }
}

// ---- Kernel 2: fold priv copies -> dis, cnt; allocate off (wave-agg atomic);
//      write per-chunk cursors curb. ----
__global__ __launch_bounds__(512) void k_fold(
    const float* __restrict__ deg_priv, const unsigned short* __restrict__ cnt_priv,
    float* __restrict__ dis, int* __restrict__ cnt, int* __restrict__ off,
    int* __restrict__ curb, int* __restrict__ cursor, int n) {

    int d = blockIdx.x * 512 + threadIdx.x;
    int lane = threadIdx.x & 63;
    int ct = 0;
    if (d < n) {
        float s = 0.f;
        #pragma unroll 4
        for (int b = 0; b < NB; ++b) {
            s  += deg_priv[(size_t)b * n + d];
            ct += (int)cnt_priv[(size_t)b * n + d];
        }
        dis[d] = (s > 0.0f) ? rsqrtf(fmaxf(s, 1e-12f)) : 0.0f;
        cnt[d] = ct;
    }

    // wave-aggregated offset allocation (CSR regions need not be d-monotonic)
    int s_incl = ct;
    #pragma unroll
    for (int o = 1; o < 64; o <<= 1) {
        int t2 = __shfl_up(s_incl, o);
        if (lane >= o) s_incl += t2;
    }
    int wtotal = __shfl(s_incl, 63);
    int base = 0;
    if (lane == 0) base = atomicAdd(cursor, wtotal);
    base = __shfl(base, 0);

    if (d < n) {
        int my0 = base + s_incl - ct;
        off[d] = my0;
        int run = my0;
        #pragma unroll 4
        for (int b = 0; b < NB; ++b) {
            curb[(size_t)b * n + d] = run;
            run += (int)cnt_priv[(size_t)b * n + d];   // L2-hot re-read
        }
    }
}

// ---- Kernel 3: bucket fill over (chunk b, node-range r); cursor row slice
//      staged in LDS (coalesced); zero device atomics. Block 0: hflag OR. ----
__global__ __launch_bounds__(512) void k_fill_lds(
    const float* __restrict__ ew, const int* __restrict__ src,
    const int* __restrict__ dst, const float* __restrict__ dis,
    const int* __restrict__ curb, int2* __restrict__ epk,
    const int* __restrict__ flagpart, int* __restrict__ hflag,
    int E, int n, int ech, int rs, int cvb) {

    __shared__ int curL[RSF_MAX];

    const int b    = blockIdx.x & (NB - 1);
    const int r    = blockIdx.x >> 7;
    const int base = r * rs;
    const int rse  = min(rs, n - base);

    if (blockIdx.x == 0) {
        // hflag zeroed by k_front (previous dispatch); OR the cvt flag parts.
        int fl = 0;
        for (int i = threadIdx.x; i < cvb; i += 512) fl |= flagpart[i];
        unsigned long long m = __ballot(fl != 0);
        if ((threadIdx.x & 63) == 0 && m) atomicOr(hflag, 1);
    }

    const int* crow = curb + (size_t)b * n + base;
    for (int i = threadIdx.x; i < rse; i += 512) curL[i] = crow[i];
    __syncthreads();

    const int e0 = b * ech, e1 = min(e0 + ech, E);
    for (int e = e0 + (int)threadIdx.x; e < e1; e += 512) {
        int d = dst[e];
        unsigned int rd_ = (unsigned int)(d - base);
        if (rd_ < (unsigned int)rse) {
            int s = src[e];
            float w = -dis[s] * ew[e] * dis[d];
            int p = atomicAdd(&curL[rd_], 1);
            epk[p] = make_int2(s, __builtin_bit_cast(int, w));
        }
    }
}

// ---- Kernel 4: gather -> writes tx/th A-fragments (kb 4-7, 12-15) directly
__global__ __launch_bounds__(256) void k_gather_bf(
    const unsigned int* __restrict__ xw, const unsigned int* __restrict__ hw,
    const int* __restrict__ off, const int* __restrict__ cntv,
    const int2* __restrict__ epk, const int* __restrict__ hflag,
    unsigned short* __restrict__ Abf, int n) {

    int d    = blockIdx.x * 4 + (threadIdx.x >> 6);
    int lane = threadIdx.x & 63;
    if (d >= n) return;
    const bool hasH = (*hflag) != 0;

    int p0 = off[d], p1 = p0 + cntv[d];
    float ax0 = 0.f, ax1 = 0.f, ah0 = 0.f, ah1 = 0.f;

    if (!hasH) {
        for (int base = p0; base < p1; base += 64) {
            int cnt = min(64, p1 - base);
            int2 my = make_int2(0, 0);
            if (lane < cnt) my = epk[base + lane];
            int   sm = my.x;
            float wm = __builtin_bit_cast(float, my.y);
            int k = 0;
            for (; k + 4 <= cnt; k += 4) {
                int   s0 = __shfl(sm, k),     s1 = __shfl(sm, k + 1);
                int   s2 = __shfl(sm, k + 2), s3 = __shfl(sm, k + 3);
                float w0 = __shfl(wm, k),     w1 = __shfl(wm, k + 1);
                float w2 = __shfl(wm, k + 2), w3 = __shfl(wm, k + 3);
                unsigned int u0 = xw[s0 * 64 + lane];
                unsigned int u1 = xw[s1 * 64 + lane];
                unsigned int u2 = xw[s2 * 64 + lane];
                unsigned int u3 = xw[s3 * 64 + lane];
                ax0 = fmaf(w0, bflo(u0), ax0); ax1 = fmaf(w0, bfhi(u0), ax1);
                ax0 = fmaf(w1, bflo(u1), ax0); ax1 = fmaf(w1, bfhi(u1), ax1);
                ax0 = fmaf(w2, bflo(u2), ax0); ax1 = fmaf(w2, bfhi(u2), ax1);
                ax0 = fmaf(w3, bflo(u3), ax0); ax1 = fmaf(w3, bfhi(u3), ax1);
            }
            for (; k < cnt; ++k) {
                int s = __shfl(sm, k);
                float w = __shfl(wm, k);
                unsigned int u = xw[s * 64 + lane];
                ax0 = fmaf(w, bflo(u), ax0); ax1 = fmaf(w, bfhi(u), ax1);
            }
        }
    } else {
        for (int base = p0; base < p1; base += 64) {
            int cnt = min(64, p1 - base);
            int2 my = make_int2(0, 0);
            if (lane < cnt) my = epk[base + lane];
            int   sm = my.x;
            float wm = __builtin_bit_cast(float, my.y);
            int k = 0;
            for (; k + 2 <= cnt; k += 2) {
                int   s0 = __shfl(sm, k), s1 = __shfl(sm, k + 1);
                float w0 = __shfl(wm, k), w1 = __shfl(wm, k + 1);
                unsigned int u0 = xw[s0 * 64 + lane];
                unsigned int v0 = hw[s0 * 64 + lane];
                unsigned int u1 = xw[s1 * 64 + lane];
                unsigned int v1 = hw[s1 * 64 + lane];
                ax0 = fmaf(w0, bflo(u0), ax0); ax1 = fmaf(w0, bfhi(u0), ax1);
                ah0 = fmaf(w0, bflo(v0), ah0); ah1 = fmaf(w0, bfhi(v0), ah1);
                ax0 = fmaf(w1, bflo(u1), ax0); ax1 = fmaf(w1, bfhi(u1), ax1);
                ah0 = fmaf(w1, bflo(v1), ah0); ah1 = fmaf(w1, bfhi(v1), ah1);
            }
            for (; k < cnt; ++k) {
                int s = __shfl(sm, k);
                float w = __shfl(wm, k);
                unsigned int u = xw[s * 64 + lane];
                unsigned int v = hw[s * 64 + lane];
                ax0 = fmaf(w, bflo(u), ax0); ax1 = fmaf(w, bfhi(u), ax1);
                ah0 = fmaf(w, bflo(v), ah0); ah1 = fmaf(w, bfhi(v), ah1);
            }
        }
    }

    unsigned int* Au = (unsigned int*)Abf;
    size_t fragT = (size_t)(d >> 4) * 16 + 4 + (lane >> 4);
    int slotu = ((d & 15) + 16 * ((lane >> 2) & 3)) * 4 + (lane & 3);
    Au[fragT * 256 + slotu] = pack2bf(ax0, ax1);
    if (hasH) Au[(fragT + 8) * 256 + slotu] = pack2bf(ah0, ah1);
}

// ---- Kernel 5: fused MFMA GEMM + LSTM epilogue ----
// Block: 8 waves own one 64-row tile (A-frags fetched once per tile).
// Wave jj: 64 rows x {16 cols of each of the 4 gates}: col-frags cf = g*8+jj.
__global__ __launch_bounds__(512) void k_gemm_lstm(
    const unsigned short* __restrict__ Abf, const unsigned short* __restrict__ Wbf,
    const int* __restrict__ hflag,
    const float* __restrict__ c, const float* __restrict__ bias,
    const float* __restrict__ wc, float* __restrict__ out, int n) {

    int rt   = blockIdx.x;            // row tile (64 rows)
    int jj   = threadIdx.x >> 6;      // 16-col slice within each gate (0..7)
    int lane = threadIdx.x & 63;
    const int kbmax = (*hflag) ? 16 : 8;

    f32x4 acc[4][4];
    #pragma unroll
    for (int mi = 0; mi < 4; ++mi)
        #pragma unroll
        for (int g = 0; g < 4; ++g)
            acc[mi][g] = (f32x4)0.0f;

    const size_t aoff = ((size_t)(rt * 4) * 16) * 512 + lane * 8;

    for (int kb = 0; kb < kbmax; ++kb) {
        bf16x8 a[4], b[4];
        #pragma unroll
        for (int mi = 0; mi < 4; ++mi)
            a[mi] = *reinterpret_cast<const bf16x8*>(Abf + aoff + (size_t)(mi * 16 + kb) * 512);
        #pragma unroll
        for (int g = 0; g < 4; ++g)
            b[g] = *reinterpret_cast<const bf16x8*>(
                Wbf + ((size_t)(g * 8 + jj) * 16 + kb) * 512 + lane * 8);
        #pragma unroll
        for (int mi = 0; mi < 4; ++mi)
            #pragma unroll
            for (int g = 0; g < 4; ++g)
                acc[mi][g] = __builtin_amdgcn_mfma_f32_16x16x32_bf16(
                                 a[mi], b[g], acc[mi][g], 0, 0, 0);
    }

    const int r0   = rt * 64;
    const int col  = jj * 16 + (lane & 15);
    const size_t NH = (size_t)n * FD;
    const float wc0 = wc[0 * FD + col], wc1 = wc[1 * FD + col], wc2 = wc[2 * FD + col];
    const float b0  = bias[0 * FD + col], b1 = bias[1 * FD + col];
    const float b2  = bias[2 * FD + col], b3 = bias[3 * FD + col];

    #pragma unroll
    for (int mi = 0; mi < 4; ++mi) {
        #pragma unroll
        for (int q = 0; q < 4; ++q) {
            int r = r0 + mi * 16 + (lane >> 4) * 4 + q;
            if (r >= n) continue;
            float cv = c[(size_t)r * FD + col];
            float gi = acc[mi][0][q] + wc0 * cv + b0;
            float gf = acc[mi][1][q] + wc1 * cv + b1;
            float gg = acc[mi][2][q] + b2;
            float iv = sigmoidf_(gi);
            float fv = sigmoidf_(gf);
            float cn = fv * cv + iv * tanhf(gg);
            float go = acc[mi][3][q] + wc2 * cn + b3;
            float hn = sigmoidf_(go) * tanhf(cn);
            size_t o = (size_t)r * FD + col;
            out[o]          = hn;
            out[NH + o]     = hn;
            out[2 * NH + o] = cn;
        }
    }
}

extern "C" void kernel_launch(void* const* d_in, const int* in_sizes, int n_in,
                              void* d_out, int out_size, void* d_ws, size_t ws_size,
                              hipStream_t stream) {
    const float* x   = (const float*)d_in[0];
    const float* ew  = (const float*)d_in[1];
    const float* h   = (const float*)d_in[2];
    const float* c   = (const float*)d_in[3];
    const float* Wx  = (const float*)d_in[4];
    const float* Wh  = (const float*)d_in[5];
    const float* b   = (const float*)d_in[6];
    const float* wc  = (const float*)d_in[7];
    const int*   src = (const int*)d_in[8];
    const int*   dst = (const int*)d_in[9];

    const int n = in_sizes[0] / FD;   // 20000  (<= NMAX)
    const int E = in_sizes[1];        // 640000

    const int Mpad = (n + 63) & ~63;              // 20032
    const int ech  = (E + NB - 1) / NB;           // 5000
    const int rsh  = (n + NRH - 1) / NRH;         // 10000 (<= RSH_MAX)
    const int rsf  = (n + NRF - 1) / NRF;         // 10000 (<= RSF_MAX)
    const int n16  = n * 16;
    const int cvb  = (n16 + 511) / 512;           // cvt section blocks (625)
    const int npf  = (n + 511) / 512;             // fold blocks (40)

    // ---- workspace layout (all regions disjoint; ws is 256MB) ----
    float* dis      = (float*)d_ws;                        // n
    int*   cnt      = (int*)(dis + n);                     // n
    int*   off      = cnt + n;                             // n+4
    int*   hflag    = off + n + 4;                         // 4
    int*   cursor   = hflag + 4;                           // 4
    int*   flagpart = cursor + 4;                          // 1280 (pad)
    int2*  epk      = (int2*)(flagpart + 1280);            // E
    unsigned int* xw = (unsigned int*)(epk + E);           // n*64
    unsigned int* hw = xw + (size_t)n * 64;                // n*64
    unsigned short* Abf = (unsigned short*)(hw + (size_t)n * 64);  // Mpad*512
    unsigned short* Wbf = Abf + (size_t)Mpad * 512;        // 512*512
    int*   curb     = (int*)(Wbf + 512 * 512);             // NB*n
    float* deg_priv = (float*)(curb + (size_t)NB * n);     // NB*n
    unsigned short* cnt_priv = (unsigned short*)(deg_priv + (size_t)NB * n); // NB*n

    k_front<<<NB * NRH + cvb + 64, 512, 0, stream>>>(
        ew, src, dst, deg_priv, cnt_priv, cursor, hflag,
        x, h, Wx, Wh, xw, hw, Abf, Wbf, flagpart,
        E, n, ech, rsh, n16, cvb);
    k_fold<<<npf, 512, 0, stream>>>(deg_priv, cnt_priv, dis, cnt, off, curb,
                                    cursor, n);
    k_fill_lds<<<NB * NRF, 512, 0, stream>>>(ew, src, dst, dis, curb, epk,
                                             flagpart, hflag, E, n, ech, rsf, cvb);
    k_gather_bf<<<(n + 3) / 4, 256, 0, stream>>>(xw, hw, off, cnt, epk, hflag, Abf, n);

    k_gemm_lstm<<<Mpad / 64, 512, 0, stream>>>(Abf, Wbf, hflag, c, b, wc,
                                               (float*)d_out, n);
}